// Round 11
// baseline (826.999 us; speedup 1.0000x reference)
//
#include <hip/hip_runtime.h>
#include <hip/hip_bf16.h>
#include <cstdint>
#include <cstddef>

typedef __attribute__((ext_vector_type(8))) short short8;
typedef __attribute__((ext_vector_type(4))) float f32x4;

#define GLL16(g, l) __builtin_amdgcn_global_load_lds(                         \
    (const __attribute__((address_space(1))) void*)(g),                        \
    (__attribute__((address_space(3))) void*)(l), 16, 0, 0)

constexpr int kB = 32, kC = 64, kL = 512;
constexpr int kPL = 16, kPN = 32;
constexpr int kH = 512, kFF = 512, kE = 8;
constexpr int kT = kB * kC * kPN;              // 65536 tokens
constexpr int kTilesPerSlot = 520;             // 512 + 8 pad tiles (fixed region)
constexpr int kMaxTiles = 2 * kTilesPerSlot;   // 1040
constexpr int kMaxPairs = kMaxTiles * 128;     // 133120

// ---------------- workspace layout (bytes) ----------------
constexpr size_t OFF_TOK  = 0;                                    // T*H bf16 = 64 MiB
constexpr size_t OFF_GU   = OFF_TOK + (size_t)kT * kH * 2;        // pairs*FF bf16
constexpr size_t OFF_TOPI = OFF_GU + (size_t)kMaxPairs * kFF * 2; // T int
constexpr size_t OFF_TOPW = OFF_TOPI + (size_t)kT * 4;            // T*2 float
constexpr size_t OFF_CCNT = OFF_TOPW + (size_t)kT * 8;            // 256*16 int
constexpr size_t OFF_COFF = OFF_CCNT + 256 * 16 * 4;              // 256*16 int
constexpr size_t OFF_EOFF = OFF_COFF + 256 * 16 * 4;              // 16 int (+pad)
constexpr size_t OFF_TILE = OFF_EOFF + 256;                       // kMaxTiles int
constexpr size_t OFF_PTOK = OFF_TILE + ((kMaxTiles * 4 + 255) & ~255ull);
constexpr size_t OFF_PW   = OFF_PTOK + (size_t)kMaxPairs * 4;
constexpr size_t OFF_DUMP = OFF_PW + (size_t)kMaxPairs * 4;       // 128*512 f32
constexpr size_t OFF_BG   = OFF_DUMP + 128 * 512 * 4;             // E*FF*H bf16
constexpr size_t OFF_BU   = OFF_BG + (size_t)kE * kFF * kH * 2;
constexpr size_t OFF_BD   = OFF_BU + (size_t)kE * kFF * kH * 2;
constexpr size_t OFF_WC   = OFF_BD + (size_t)kE * kH * kFF * 2;   // 8*16 double
constexpr size_t OFF_BC   = OFF_WC + 8 * 16 * 8;                  // 8 double

// ---------------- small kernels ----------------
__global__ __launch_bounds__(256) void k_conv3(const float* __restrict__ a,
                                               const float* __restrict__ b,
                                               const float* __restrict__ c,
                                               __hip_bfloat16* __restrict__ da,
                                               __hip_bfloat16* __restrict__ db,
                                               __hip_bfloat16* __restrict__ dc, int n) {
  for (int i = blockIdx.x * blockDim.x + threadIdx.x; i < 3 * n; i += gridDim.x * blockDim.x) {
    int reg = i / n, j = i - reg * n;
    const float* s = (reg == 0) ? a : (reg == 1) ? b : c;
    __hip_bfloat16* d = (reg == 0) ? da : (reg == 1) ? db : dc;
    d[j] = __float2bfloat16(s[j]);
  }
}

// Wcomb[e][l] = sum_d Wg[e][d]*Wp[d][l] (fp64); bconst[e] = sum_d bp[d]*Wg[e][d]
__global__ void k_wcomb(const float* __restrict__ Wg, const float* __restrict__ Wp,
                        const float* __restrict__ bp, double* __restrict__ wc,
                        double* __restrict__ bc) {
  int tid = threadIdx.x;  // 128
  int e = tid >> 4, l = tid & 15;
  double s = 0.0;
  for (int d = 0; d < kH; ++d) s += (double)Wg[e * kH + d] * (double)Wp[d * kPL + l];
  wc[e * kPL + l] = s;
  if (l == 0) {
    double b = 0.0;
    for (int d = 0; d < kH; ++d) b += (double)Wg[e * kH + d] * (double)bp[d];
    bc[e] = b;
  }
}

// patchify + project: tok[t][d] = bf16( sum_l x[bc, p*16+l]*Wp[d][l] + bp[d] )
__global__ __launch_bounds__(256) void k_patch(const float* __restrict__ x,
                                               const float* __restrict__ Wp,
                                               const float* __restrict__ bp,
                                               __hip_bfloat16* __restrict__ tok) {
  __shared__ float sWp[512 * 17];
  __shared__ float sx[128];
  __shared__ float sbp[512];
  int bb = blockIdx.x;            // 8192 blocks
  int bc = bb >> 2, pg = bb & 3;
  int tid = threadIdx.x;
  for (int i = tid; i < 512 * 16; i += 256) sWp[(i >> 4) * 17 + (i & 15)] = Wp[i];
  if (tid < 128) sx[tid] = x[(size_t)bc * 512 + pg * 128 + tid];
  for (int i = tid; i < 512; i += 256) sbp[i] = bp[i];
  __syncthreads();
  for (int tl = 0; tl < 8; ++tl) {
    int t = bc * kPN + pg * 8 + tl;
    const float* xp = &sx[tl * 16];
    for (int d = tid; d < 512; d += 256) {
      float s = sbp[d];
#pragma unroll
      for (int l = 0; l < 16; ++l) s += xp[l] * sWp[d * 17 + l];
      tok[(size_t)t * kH + d] = __float2bfloat16(s);
    }
  }
}

// router: fp64 logits via fused (Wp^T Wg), fp64 softmax, top-2.
__global__ __launch_bounds__(256) void k_router(const float* __restrict__ x,
                                                const double* __restrict__ wc,
                                                const double* __restrict__ bc,
                                                int* __restrict__ topi,
                                                float* __restrict__ topw,
                                                int* __restrict__ chunkCnt) {
  int t = blockIdx.x * 256 + threadIdx.x;
  int bci = t >> 5, p = t & 31;
  const float* xp = &x[(size_t)bci * 512 + p * 16];
  double xl[16];
#pragma unroll
  for (int l = 0; l < 16; ++l) xl[l] = (double)xp[l];
  double lo[8];
  double m = -1e300;
#pragma unroll
  for (int e = 0; e < 8; ++e) {
    double s = bc[e];
#pragma unroll
    for (int l = 0; l < 16; ++l) s += xl[l] * wc[e * 16 + l];
    lo[e] = s;
    m = fmax(m, s);
  }
  double den = 0.0;
#pragma unroll
  for (int e = 0; e < 8; ++e) {
    lo[e] = exp(lo[e] - m);
    den += lo[e];
  }
  int i1 = 0;
  double v1 = lo[0];
#pragma unroll
  for (int e = 1; e < 8; ++e)
    if (lo[e] > v1) { v1 = lo[e]; i1 = e; }
  int i2 = -1;
  double v2 = -1.0;
#pragma unroll
  for (int e = 0; e < 8; ++e)
    if (e != i1 && lo[e] > v2) { v2 = lo[e]; i2 = e; }
  topi[t] = i1 | (i2 << 4);
  topw[2 * t] = (float)(v1 / den);
  topw[2 * t + 1] = (float)(v2 / den);

  __shared__ int wsum[16][4];
  int wave = threadIdx.x >> 6, lane = threadIdx.x & 63;
#pragma unroll
  for (int seg = 0; seg < 16; ++seg) {
    int e = seg & 7;
    bool sel = (seg < 8) ? (i1 == e) : (i2 == e);
    unsigned long long mm = __ballot(sel);
    if (lane == 0) wsum[seg][wave] = __popcll(mm);
  }
  __syncthreads();
  if (threadIdx.x < 16)
    chunkCnt[blockIdx.x * 16 + threadIdx.x] =
        wsum[threadIdx.x][0] + wsum[threadIdx.x][1] + wsum[threadIdx.x][2] + wsum[threadIdx.x][3];
}

// scan: per-segment chunk offsets (LDS-staged), segment bases, tile table, pad fill
__global__ __launch_bounds__(256) void k_scan(const int* __restrict__ chunkCnt,
                                              int* __restrict__ chunkOff,
                                              int* __restrict__ eoff,
                                              int* __restrict__ tileExpert,
                                              int* __restrict__ pairTok,
                                              float* __restrict__ pairW) {
  int tid = threadIdx.x;
  __shared__ int cnt[256 * 16];
  __shared__ int coff[256 * 16];
  for (int i = tid; i < 256 * 16; i += 256) cnt[i] = chunkCnt[i];
  __syncthreads();
  __shared__ int totals[16];
  __shared__ int base[16];
  __shared__ int padded[16];
  if (tid < 16) {
    int run = 0;
    for (int c = 0; c < 256; ++c) {
      coff[c * 16 + tid] = run;
      run += cnt[c * 16 + tid];
    }
    totals[tid] = run;
  }
  __syncthreads();
  for (int i = tid; i < 256 * 16; i += 256) chunkOff[i] = coff[i];
  if (tid == 0) {
    for (int s = 0; s < 2; ++s) {
      int b = s * kTilesPerSlot * 128;
      for (int e = 0; e < 8; ++e) {
        int seg = s * 8 + e;
        base[seg] = b;
        padded[seg] = (totals[seg] + 127) & ~127;
        b += padded[seg];
      }
    }
  }
  __syncthreads();
  if (tid < 16) eoff[tid] = base[tid];
  for (int tI = tid; tI < kMaxTiles; tI += 256) tileExpert[tI] = -1;
  __syncthreads();
  for (int seg = 0; seg < 16; ++seg) {
    int e = seg & 7;
    int tile0 = base[seg] >> 7, nt = padded[seg] >> 7;
    for (int tI = tid; tI < nt; tI += 256) tileExpert[tile0 + tI] = e;
    for (int p = base[seg] + totals[seg] + tid; p < base[seg] + padded[seg]; p += 256) {
      pairTok[p] = -1;  // pad sentinel
      pairW[p] = 0.f;
    }
  }
}

// fill: deterministic token-ordered compaction into per-(slot,expert) segments
__global__ __launch_bounds__(256) void k_fill(const int* __restrict__ topi,
                                              const float* __restrict__ topw,
                                              const int* __restrict__ chunkOff,
                                              const int* __restrict__ eoff,
                                              int* __restrict__ pairTok,
                                              float* __restrict__ pairW) {
  int chunk = blockIdx.x;
  int t = chunk * 256 + threadIdx.x;
  int pk = topi[t];
  int i1 = pk & 15, i2 = (pk >> 4) & 15;
  float w1 = topw[2 * t], w2 = topw[2 * t + 1];
  int wave = threadIdx.x >> 6, lane = threadIdx.x & 63;
  __shared__ int wsum[16][4];
  int pre[16];
  bool sel[16];
#pragma unroll
  for (int seg = 0; seg < 16; ++seg) {
    int e = seg & 7;
    sel[seg] = (seg < 8) ? (i1 == e) : (i2 == e);
    unsigned long long mm = __ballot(sel[seg]);
    pre[seg] = __popcll(mm & ((1ull << lane) - 1));
    if (lane == 0) wsum[seg][wave] = __popcll(mm);
  }
  __syncthreads();
#pragma unroll
  for (int seg = 0; seg < 16; ++seg) {
    if (!sel[seg]) continue;
    int woff = 0;
    for (int w = 0; w < wave; ++w) woff += wsum[seg][w];
    int pos = eoff[seg] + chunkOff[chunk * 16 + seg] + woff + pre[seg];
    pairTok[pos] = t;
    pairW[pos] = (seg < 8) ? w1 : w2;
  }
}

// ---------------- sparse GEMM kernels (128x128xBK=64 bf16 MFMA) ----------------
// BK=64 single-buffer (r10, +35 µs win): one barrier pair per 64 MFMA/wave.
// 8-chunk XOR swizzle: physical chunk p at row holds logical p ^ (row&7) (r4/r10).
// N-block-fastest grid (r6). r11: __launch_bounds__(256,3) -> 3 blocks/CU
// (LDS 48/49 KB fits; VGPR cap 170 > measured 108); gateup epilogue now stages
// C through the dead As region (bf16 [32][136] = 8.7 KB < 16 KB As -> no
// cross-array layout assumption, r8 lesson) for 16B coalesced GU stores.

// gu[pairRow][col] = silu(tok[pairTok[row]] @ Wgate[e]^T) * (tok[...] @ Wup[e]^T)
__global__ __launch_bounds__(256, 3) void k_gateup_sp(const __hip_bfloat16* __restrict__ tok,
                                                      const __hip_bfloat16* __restrict__ Wg0,
                                                      const __hip_bfloat16* __restrict__ Wu0,
                                                      const int* __restrict__ pairTok,
                                                      const int* __restrict__ tileExpert,
                                                      __hip_bfloat16* __restrict__ GU) {
  const int tileIdx = blockIdx.x >> 2;
  const int e = tileExpert[tileIdx];
  if (e < 0) return;
  __shared__ __hip_bfloat16 As[128 * 64];   // 16 KB each
  __shared__ __hip_bfloat16 Bgs[128 * 64];
  __shared__ __hip_bfloat16 Bus[128 * 64];
  const int tid = threadIdx.x;
  const int wid = tid >> 6, lane = tid & 63;
  const int tileBase = tileIdx * 128, tileN = (blockIdx.x & 3) * 128;
  const int wr = wid >> 1, wcol = wid & 1;
  const int r = lane & 15, kq = lane >> 4;

  f32x4 accg[4][4] = {};
  f32x4 accu[4][4] = {};

  const char* Ab = (const char*)tok;
  const char* Bgb = (const char*)(Wg0 + (size_t)e * kFF * kH);
  const char* Bub = (const char*)(Wu0 + (size_t)e * kFF * kH);

  int rowS[4], colS[4];
  size_t tokS[4];
#pragma unroll
  for (int s = 0; s < 4; ++s) {
    int off = wid * 1024 + lane * 16 + s * 4096;
    rowS[s] = off >> 7;                         // 128-B rows
    int p = (off & 127) >> 4;                   // physical chunk 0..7
    colS[s] = ((p ^ (rowS[s] & 7)) << 4);       // pre-swizzled global col (bytes)
    int ti = pairTok[tileBase + rowS[s]];
    tokS[s] = (size_t)(ti < 0 ? 0 : ti);
  }

#pragma unroll 1
  for (int kt = 0; kt < 8; ++kt) {
    const int kb = kt * 128;  // byte offset within 1024-B token row
#pragma unroll
    for (int s = 0; s < 4; ++s) {
      GLL16(Ab + tokS[s] * 1024 + kb + colS[s], (char*)As + wid * 1024 + s * 4096);
      GLL16(Bgb + (size_t)(tileN + rowS[s]) * 1024 + kb + colS[s],
            (char*)Bgs + wid * 1024 + s * 4096);
      GLL16(Bub + (size_t)(tileN + rowS[s]) * 1024 + kb + colS[s],
            (char*)Bus + wid * 1024 + s * 4096);
    }
    __syncthreads();

#pragma unroll
    for (int kk = 0; kk < 2; ++kk) {
      short8 a[4], bg[4], bu[4];
#pragma unroll
      for (int i = 0; i < 4; ++i) {
        int row = wr * 64 + i * 16 + r;
        int pc = (kk * 4 + kq) ^ (row & 7);
        a[i] = *(const short8*)&As[row * 64 + pc * 8];
      }
#pragma unroll
      for (int j = 0; j < 4; ++j) {
        int row = wcol * 64 + j * 16 + r;
        int pc = (kk * 4 + kq) ^ (row & 7);
        bg[j] = *(const short8*)&Bgs[row * 64 + pc * 8];
        bu[j] = *(const short8*)&Bus[row * 64 + pc * 8];
      }
#pragma unroll
      for (int i = 0; i < 4; ++i)
#pragma unroll
        for (int j = 0; j < 4; ++j) {
          accg[i][j] = __builtin_amdgcn_mfma_f32_16x16x32_bf16(a[i], bg[j], accg[i][j], 0, 0, 0);
          accu[i][j] = __builtin_amdgcn_mfma_f32_16x16x32_bf16(a[i], bu[j], accu[i][j], 0, 0, 0);
        }
    }
    __syncthreads();
  }

  // ---- LDS-transpose epilogue (bf16) staged entirely within the dead As
  // region: [32][136] bf16 = 8.7 KB <= 16 KB. 4 batches of 32 rows; then each
  // thread stores 16 contiguous bf16 (2 x short8 = 32 B) per batch.
  __hip_bfloat16* Csb = (__hip_bfloat16*)&As[0];
  const int rowl = tid >> 3;           // 0..31
  const int cbase = (tid & 7) * 16;    // 0..112
#pragma unroll
  for (int batch = 0; batch < 4; ++batch) {
    __syncthreads();  // As free (K-loop done / prev batch consumed)
    if (wr == (batch >> 1)) {
      int bi0 = (batch & 1) * 2;
#pragma unroll
      for (int ii = 0; ii < 2; ++ii) {
        int i = bi0 + ii;
#pragma unroll
        for (int j = 0; j < 4; ++j) {
          int cl = wcol * 64 + j * 16 + r;
#pragma unroll
          for (int q = 0; q < 4; ++q) {
            int rl = ii * 16 + kq * 4 + q;
            float g = accg[i][j][q], u = accu[i][j][q];
            float val = g / (1.f + __expf(-g)) * u;
            Csb[rl * 136 + cl] = __float2bfloat16(val);
          }
        }
      }
    }
    __syncthreads();
    int row = tileBase + batch * 32 + rowl;
    __hip_bfloat16* gout = GU + (size_t)row * kFF + tileN + cbase;
    const __hip_bfloat16* crow = &Csb[rowl * 136 + cbase];
    *(short8*)(gout) = *(const short8*)(crow);
    *(short8*)(gout + 8) = *(const short8*)(crow + 8);
  }
}

// out[pairTok[row]] (=|+=) pairW[row] * (gu[row] @ Wdown[e]^T)  — no atomics.
__global__ __launch_bounds__(256, 3) void k_down_sp(const __hip_bfloat16* __restrict__ GU,
                                                    const __hip_bfloat16* __restrict__ Wd0,
                                                    const int* __restrict__ pairTok,
                                                    const float* __restrict__ pairW,
                                                    const int* __restrict__ tileExpert,
                                                    float* __restrict__ out,
                                                    float* __restrict__ dump,
                                                    int tileOff, int first) {
  const int tile = tileOff + (blockIdx.x >> 2);
  const int e = tileExpert[tile];
  if (e < 0) return;
  __shared__ __hip_bfloat16 As[128 * 64];
  __shared__ __hip_bfloat16 Bs[128 * 64];
  __shared__ float Cs[32 * 132];  // dedicated epilogue staging (16.9 KB)
  const int tid = threadIdx.x;
  const int wid = tid >> 6, lane = tid & 63;
  const int tileBase = tile * 128, tileN = (blockIdx.x & 3) * 128;
  const int wr = wid >> 1, wcol = wid & 1;
  const int r = lane & 15, kq = lane >> 4;

  f32x4 acc[4][4] = {};

  const char* Ab = (const char*)GU;
  const char* Bb = (const char*)(Wd0 + (size_t)e * kH * kFF);

  int rowS[4], colS[4];
#pragma unroll
  for (int s = 0; s < 4; ++s) {
    int off = wid * 1024 + lane * 16 + s * 4096;
    rowS[s] = off >> 7;
    int p = (off & 127) >> 4;
    colS[s] = ((p ^ (rowS[s] & 7)) << 4);
  }

#pragma unroll 1
  for (int kt = 0; kt < 8; ++kt) {
    const int kb = kt * 128;
#pragma unroll
    for (int s = 0; s < 4; ++s) {
      GLL16(Ab + (size_t)(tileBase + rowS[s]) * 1024 + kb + colS[s],
            (char*)As + wid * 1024 + s * 4096);
      GLL16(Bb + (size_t)(tileN + rowS[s]) * 1024 + kb + colS[s],
            (char*)Bs + wid * 1024 + s * 4096);
    }
    __syncthreads();

#pragma unroll
    for (int kk = 0; kk < 2; ++kk) {
      short8 a[4], b[4];
#pragma unroll
      for (int i = 0; i < 4; ++i) {
        int row = wr * 64 + i * 16 + r;
        int pc = (kk * 4 + kq) ^ (row & 7);
        a[i] = *(const short8*)&As[row * 64 + pc * 8];
      }
#pragma unroll
      for (int j = 0; j < 4; ++j) {
        int row = wcol * 64 + j * 16 + r;
        int pc = (kk * 4 + kq) ^ (row & 7);
        b[j] = *(const short8*)&Bs[row * 64 + pc * 8];
      }
#pragma unroll
      for (int i = 0; i < 4; ++i)
#pragma unroll
        for (int j = 0; j < 4; ++j)
          acc[i][j] = __builtin_amdgcn_mfma_f32_16x16x32_bf16(a[i], b[j], acc[i][j], 0, 0, 0);
    }
    __syncthreads();
  }

  // ---- LDS-transpose epilogue: 4 batches of 32 rows through dedicated Cs
  const int rowl = tid >> 3;            // 0..31
  const int cbase = (tid & 7) * 16;     // 0..112, f32 col within 128
#pragma unroll
  for (int batch = 0; batch < 4; ++batch) {
    __syncthreads();
    if (wr == (batch >> 1)) {
      int bi0 = (batch & 1) * 2;
#pragma unroll
      for (int ii = 0; ii < 2; ++ii) {
        int i = bi0 + ii;
#pragma unroll
        for (int j = 0; j < 4; ++j) {
          int cl = wcol * 64 + j * 16 + r;
#pragma unroll
          for (int q = 0; q < 4; ++q) {
            int rl = ii * 16 + kq * 4 + q;
            Cs[rl * 132 + cl] = acc[i][j][q];
          }
        }
      }
    }
    __syncthreads();
    int prow = tileBase + batch * 32 + rowl;
    float wv = pairW[prow];
    int tk = pairTok[prow];
    float* orow = (tk >= 0) ? out + (size_t)tk * kH + tileN + cbase
                            : dump + (size_t)(prow & 127) * kH + tileN + cbase;
    const float* crow = &Cs[rowl * 132 + cbase];
#pragma unroll
    for (int c = 0; c < 4; ++c) {
      f32x4 v = *(const f32x4*)(crow + c * 4);
      v *= wv;
      if (first) {
        *(f32x4*)(orow + c * 4) = v;
      } else {
        f32x4 o = *(const f32x4*)(orow + c * 4);
        *(f32x4*)(orow + c * 4) = o + v;
      }
    }
  }
}

// ---------------- launcher ----------------
extern "C" void kernel_launch(void* const* d_in, const int* in_sizes, int n_in,
                              void* d_out, int out_size, void* d_ws, size_t ws_size,
                              hipStream_t stream) {
  const float* x = (const float*)d_in[0];
  const float* Wp = (const float*)d_in[1];
  const float* bp = (const float*)d_in[2];
  const float* Wg = (const float*)d_in[3];
  const float* Wgate = (const float*)d_in[4];
  const float* Wup = (const float*)d_in[5];
  const float* Wdown = (const float*)d_in[6];
  float* out = (float*)d_out;

  char* ws = (char*)d_ws;
  __hip_bfloat16* tok = (__hip_bfloat16*)(ws + OFF_TOK);
  __hip_bfloat16* gu = (__hip_bfloat16*)(ws + OFF_GU);
  int* topi = (int*)(ws + OFF_TOPI);
  float* topw = (float*)(ws + OFF_TOPW);
  int* chunkCnt = (int*)(ws + OFF_CCNT);
  int* chunkOff = (int*)(ws + OFF_COFF);
  int* eoff = (int*)(ws + OFF_EOFF);
  int* tileExpert = (int*)(ws + OFF_TILE);
  int* pairTok = (int*)(ws + OFF_PTOK);
  float* pairW = (float*)(ws + OFF_PW);
  float* dump = (float*)(ws + OFF_DUMP);
  __hip_bfloat16* bgw = (__hip_bfloat16*)(ws + OFF_BG);
  __hip_bfloat16* buw = (__hip_bfloat16*)(ws + OFF_BU);
  __hip_bfloat16* bdw = (__hip_bfloat16*)(ws + OFF_BD);
  double* wc = (double*)(ws + OFF_WC);
  double* bcv = (double*)(ws + OFF_BC);

  const int nw = kE * kFF * kH;
  k_conv3<<<3072, 256, 0, stream>>>(Wgate, Wup, Wdown, bgw, buw, bdw, nw);
  k_wcomb<<<1, 128, 0, stream>>>(Wg, Wp, bp, wc, bcv);
  k_patch<<<8192, 256, 0, stream>>>(x, Wp, bp, tok);
  k_router<<<256, 256, 0, stream>>>(x, wc, bcv, topi, topw, chunkCnt);
  k_scan<<<1, 256, 0, stream>>>(chunkCnt, chunkOff, eoff, tileExpert, pairTok, pairW);
  k_fill<<<256, 256, 0, stream>>>(topi, topw, chunkOff, eoff, pairTok, pairW);

  k_gateup_sp<<<kMaxTiles * 4, 256, 0, stream>>>(tok, bgw, buw, pairTok, tileExpert, gu);
  k_down_sp<<<kTilesPerSlot * 4, 256, 0, stream>>>(gu, bdw, pairTok, pairW, tileExpert, out,
                                                   dump, 0, 1);
  k_down_sp<<<kTilesPerSlot * 4, 256, 0, stream>>>(gu, bdw, pairTok, pairW, tileExpert, out,
                                                   dump, kTilesPerSlot, 0);
}

// Round 12
// 519.639 us; speedup vs baseline: 1.5915x; 1.5915x over previous
//
#include <hip/hip_runtime.h>
#include <hip/hip_bf16.h>
#include <cstdint>
#include <cstddef>

typedef __attribute__((ext_vector_type(8))) short short8;
typedef __attribute__((ext_vector_type(4))) float f32x4;

#define GLL16(g, l) __builtin_amdgcn_global_load_lds(                         \
    (const __attribute__((address_space(1))) void*)(g),                        \
    (__attribute__((address_space(3))) void*)(l), 16, 0, 0)

constexpr int kB = 32, kC = 64, kL = 512;
constexpr int kPL = 16, kPN = 32;
constexpr int kH = 512, kFF = 512, kE = 8;
constexpr int kT = kB * kC * kPN;              // 65536 tokens
constexpr int kTilesPerSlot = 520;             // 512 + 8 pad tiles (fixed region)
constexpr int kMaxTiles = 2 * kTilesPerSlot;   // 1040
constexpr int kMaxPairs = kMaxTiles * 128;     // 133120

// ---------------- workspace layout (bytes) ----------------
constexpr size_t OFF_TOK  = 0;                                    // T*H bf16 = 64 MiB
constexpr size_t OFF_GU   = OFF_TOK + (size_t)kT * kH * 2;        // pairs*FF bf16
constexpr size_t OFF_TOPI = OFF_GU + (size_t)kMaxPairs * kFF * 2; // T int
constexpr size_t OFF_TOPW = OFF_TOPI + (size_t)kT * 4;            // T*2 float
constexpr size_t OFF_CCNT = OFF_TOPW + (size_t)kT * 8;            // 256*16 int
constexpr size_t OFF_COFF = OFF_CCNT + 256 * 16 * 4;              // 256*16 int
constexpr size_t OFF_EOFF = OFF_COFF + 256 * 16 * 4;              // 16 int (+pad)
constexpr size_t OFF_TILE = OFF_EOFF + 256;                       // kMaxTiles int
constexpr size_t OFF_PTOK = OFF_TILE + ((kMaxTiles * 4 + 255) & ~255ull);
constexpr size_t OFF_PW   = OFF_PTOK + (size_t)kMaxPairs * 4;
constexpr size_t OFF_DUMP = OFF_PW + (size_t)kMaxPairs * 4;       // 128*512 f32
constexpr size_t OFF_BG   = OFF_DUMP + 128 * 512 * 4;             // E*FF*H bf16
constexpr size_t OFF_BU   = OFF_BG + (size_t)kE * kFF * kH * 2;
constexpr size_t OFF_BD   = OFF_BU + (size_t)kE * kFF * kH * 2;
constexpr size_t OFF_WC   = OFF_BD + (size_t)kE * kH * kFF * 2;   // 8*16 double
constexpr size_t OFF_BC   = OFF_WC + 8 * 16 * 8;                  // 8 double

// ---------------- small kernels ----------------
__global__ __launch_bounds__(256) void k_conv3(const float* __restrict__ a,
                                               const float* __restrict__ b,
                                               const float* __restrict__ c,
                                               __hip_bfloat16* __restrict__ da,
                                               __hip_bfloat16* __restrict__ db,
                                               __hip_bfloat16* __restrict__ dc, int n) {
  for (int i = blockIdx.x * blockDim.x + threadIdx.x; i < 3 * n; i += gridDim.x * blockDim.x) {
    int reg = i / n, j = i - reg * n;
    const float* s = (reg == 0) ? a : (reg == 1) ? b : c;
    __hip_bfloat16* d = (reg == 0) ? da : (reg == 1) ? db : dc;
    d[j] = __float2bfloat16(s[j]);
  }
}

// Wcomb[e][l] = sum_d Wg[e][d]*Wp[d][l] (fp64); bconst[e] = sum_d bp[d]*Wg[e][d]
__global__ void k_wcomb(const float* __restrict__ Wg, const float* __restrict__ Wp,
                        const float* __restrict__ bp, double* __restrict__ wc,
                        double* __restrict__ bc) {
  int tid = threadIdx.x;  // 128
  int e = tid >> 4, l = tid & 15;
  double s = 0.0;
  for (int d = 0; d < kH; ++d) s += (double)Wg[e * kH + d] * (double)Wp[d * kPL + l];
  wc[e * kPL + l] = s;
  if (l == 0) {
    double b = 0.0;
    for (int d = 0; d < kH; ++d) b += (double)Wg[e * kH + d] * (double)bp[d];
    bc[e] = b;
  }
}

// patchify + project: tok[t][d] = bf16( sum_l x[bc, p*16+l]*Wp[d][l] + bp[d] )
__global__ __launch_bounds__(256) void k_patch(const float* __restrict__ x,
                                               const float* __restrict__ Wp,
                                               const float* __restrict__ bp,
                                               __hip_bfloat16* __restrict__ tok) {
  __shared__ float sWp[512 * 17];
  __shared__ float sx[128];
  __shared__ float sbp[512];
  int bb = blockIdx.x;            // 8192 blocks
  int bc = bb >> 2, pg = bb & 3;
  int tid = threadIdx.x;
  for (int i = tid; i < 512 * 16; i += 256) sWp[(i >> 4) * 17 + (i & 15)] = Wp[i];
  if (tid < 128) sx[tid] = x[(size_t)bc * 512 + pg * 128 + tid];
  for (int i = tid; i < 512; i += 256) sbp[i] = bp[i];
  __syncthreads();
  for (int tl = 0; tl < 8; ++tl) {
    int t = bc * kPN + pg * 8 + tl;
    const float* xp = &sx[tl * 16];
    for (int d = tid; d < 512; d += 256) {
      float s = sbp[d];
#pragma unroll
      for (int l = 0; l < 16; ++l) s += xp[l] * sWp[d * 17 + l];
      tok[(size_t)t * kH + d] = __float2bfloat16(s);
    }
  }
}

// router: fp64 logits via fused (Wp^T Wg), fp64 softmax, top-2.
__global__ __launch_bounds__(256) void k_router(const float* __restrict__ x,
                                                const double* __restrict__ wc,
                                                const double* __restrict__ bc,
                                                int* __restrict__ topi,
                                                float* __restrict__ topw,
                                                int* __restrict__ chunkCnt) {
  int t = blockIdx.x * 256 + threadIdx.x;
  int bci = t >> 5, p = t & 31;
  const float* xp = &x[(size_t)bci * 512 + p * 16];
  double xl[16];
#pragma unroll
  for (int l = 0; l < 16; ++l) xl[l] = (double)xp[l];
  double lo[8];
  double m = -1e300;
#pragma unroll
  for (int e = 0; e < 8; ++e) {
    double s = bc[e];
#pragma unroll
    for (int l = 0; l < 16; ++l) s += xl[l] * wc[e * 16 + l];
    lo[e] = s;
    m = fmax(m, s);
  }
  double den = 0.0;
#pragma unroll
  for (int e = 0; e < 8; ++e) {
    lo[e] = exp(lo[e] - m);
    den += lo[e];
  }
  int i1 = 0;
  double v1 = lo[0];
#pragma unroll
  for (int e = 1; e < 8; ++e)
    if (lo[e] > v1) { v1 = lo[e]; i1 = e; }
  int i2 = -1;
  double v2 = -1.0;
#pragma unroll
  for (int e = 0; e < 8; ++e)
    if (e != i1 && lo[e] > v2) { v2 = lo[e]; i2 = e; }
  topi[t] = i1 | (i2 << 4);
  topw[2 * t] = (float)(v1 / den);
  topw[2 * t + 1] = (float)(v2 / den);

  __shared__ int wsum[16][4];
  int wave = threadIdx.x >> 6, lane = threadIdx.x & 63;
#pragma unroll
  for (int seg = 0; seg < 16; ++seg) {
    int e = seg & 7;
    bool sel = (seg < 8) ? (i1 == e) : (i2 == e);
    unsigned long long mm = __ballot(sel);
    if (lane == 0) wsum[seg][wave] = __popcll(mm);
  }
  __syncthreads();
  if (threadIdx.x < 16)
    chunkCnt[blockIdx.x * 16 + threadIdx.x] =
        wsum[threadIdx.x][0] + wsum[threadIdx.x][1] + wsum[threadIdx.x][2] + wsum[threadIdx.x][3];
}

// scan: per-segment chunk offsets (LDS-staged), segment bases, tile table, pad fill
__global__ __launch_bounds__(256) void k_scan(const int* __restrict__ chunkCnt,
                                              int* __restrict__ chunkOff,
                                              int* __restrict__ eoff,
                                              int* __restrict__ tileExpert,
                                              int* __restrict__ pairTok,
                                              float* __restrict__ pairW) {
  int tid = threadIdx.x;
  __shared__ int cnt[256 * 16];
  __shared__ int coff[256 * 16];
  for (int i = tid; i < 256 * 16; i += 256) cnt[i] = chunkCnt[i];
  __syncthreads();
  __shared__ int totals[16];
  __shared__ int base[16];
  __shared__ int padded[16];
  if (tid < 16) {
    int run = 0;
    for (int c = 0; c < 256; ++c) {
      coff[c * 16 + tid] = run;
      run += cnt[c * 16 + tid];
    }
    totals[tid] = run;
  }
  __syncthreads();
  for (int i = tid; i < 256 * 16; i += 256) chunkOff[i] = coff[i];
  if (tid == 0) {
    for (int s = 0; s < 2; ++s) {
      int b = s * kTilesPerSlot * 128;
      for (int e = 0; e < 8; ++e) {
        int seg = s * 8 + e;
        base[seg] = b;
        padded[seg] = (totals[seg] + 127) & ~127;
        b += padded[seg];
      }
    }
  }
  __syncthreads();
  if (tid < 16) eoff[tid] = base[tid];
  for (int tI = tid; tI < kMaxTiles; tI += 256) tileExpert[tI] = -1;
  __syncthreads();
  for (int seg = 0; seg < 16; ++seg) {
    int e = seg & 7;
    int tile0 = base[seg] >> 7, nt = padded[seg] >> 7;
    for (int tI = tid; tI < nt; tI += 256) tileExpert[tile0 + tI] = e;
    for (int p = base[seg] + totals[seg] + tid; p < base[seg] + padded[seg]; p += 256) {
      pairTok[p] = -1;  // pad sentinel
      pairW[p] = 0.f;
    }
  }
}

// fill: deterministic token-ordered compaction into per-(slot,expert) segments
__global__ __launch_bounds__(256) void k_fill(const int* __restrict__ topi,
                                              const float* __restrict__ topw,
                                              const int* __restrict__ chunkOff,
                                              const int* __restrict__ eoff,
                                              int* __restrict__ pairTok,
                                              float* __restrict__ pairW) {
  int chunk = blockIdx.x;
  int t = chunk * 256 + threadIdx.x;
  int pk = topi[t];
  int i1 = pk & 15, i2 = (pk >> 4) & 15;
  float w1 = topw[2 * t], w2 = topw[2 * t + 1];
  int wave = threadIdx.x >> 6, lane = threadIdx.x & 63;
  __shared__ int wsum[16][4];
  int pre[16];
  bool sel[16];
#pragma unroll
  for (int seg = 0; seg < 16; ++seg) {
    int e = seg & 7;
    sel[seg] = (seg < 8) ? (i1 == e) : (i2 == e);
    unsigned long long mm = __ballot(sel[seg]);
    pre[seg] = __popcll(mm & ((1ull << lane) - 1));
    if (lane == 0) wsum[seg][wave] = __popcll(mm);
  }
  __syncthreads();
#pragma unroll
  for (int seg = 0; seg < 16; ++seg) {
    if (!sel[seg]) continue;
    int woff = 0;
    for (int w = 0; w < wave; ++w) woff += wsum[seg][w];
    int pos = eoff[seg] + chunkOff[chunk * 16 + seg] + woff + pre[seg];
    pairTok[pos] = t;
    pairW[pos] = (seg < 8) ? w1 : w2;
  }
}

// ---------------- sparse GEMM kernels (128x128xBK=64 bf16 MFMA) ----------------
// BK=64 single-buffer (r10): one barrier pair per 64 MFMA/wave.
// 8-chunk XOR swizzle: physical chunk p at row holds logical p ^ (row&7).
// N-block-fastest grid (r6). LDS-transpose epilogues (r9/r11).
// r12: __launch_bounds__ back to (256,2) — r11's (256,3) capped VGPR at ~170,
// spilling the 128 accumulator regs to scratch (VGPR 84, +1.4 GB scratch
// traffic, MfmaUtil 35->11%). The allocator needs ~190+; cap must stay 256.

// gu[pairRow][col] = silu(tok[pairTok[row]] @ Wgate[e]^T) * (tok[...] @ Wup[e]^T)
__global__ __launch_bounds__(256, 2) void k_gateup_sp(const __hip_bfloat16* __restrict__ tok,
                                                      const __hip_bfloat16* __restrict__ Wg0,
                                                      const __hip_bfloat16* __restrict__ Wu0,
                                                      const int* __restrict__ pairTok,
                                                      const int* __restrict__ tileExpert,
                                                      __hip_bfloat16* __restrict__ GU) {
  const int tileIdx = blockIdx.x >> 2;
  const int e = tileExpert[tileIdx];
  if (e < 0) return;
  __shared__ __hip_bfloat16 As[128 * 64];   // 16 KB each
  __shared__ __hip_bfloat16 Bgs[128 * 64];
  __shared__ __hip_bfloat16 Bus[128 * 64];
  const int tid = threadIdx.x;
  const int wid = tid >> 6, lane = tid & 63;
  const int tileBase = tileIdx * 128, tileN = (blockIdx.x & 3) * 128;
  const int wr = wid >> 1, wcol = wid & 1;
  const int r = lane & 15, kq = lane >> 4;

  f32x4 accg[4][4] = {};
  f32x4 accu[4][4] = {};

  const char* Ab = (const char*)tok;
  const char* Bgb = (const char*)(Wg0 + (size_t)e * kFF * kH);
  const char* Bub = (const char*)(Wu0 + (size_t)e * kFF * kH);

  int rowS[4], colS[4];
  size_t tokS[4];
#pragma unroll
  for (int s = 0; s < 4; ++s) {
    int off = wid * 1024 + lane * 16 + s * 4096;
    rowS[s] = off >> 7;                         // 128-B rows
    int p = (off & 127) >> 4;                   // physical chunk 0..7
    colS[s] = ((p ^ (rowS[s] & 7)) << 4);       // pre-swizzled global col (bytes)
    int ti = pairTok[tileBase + rowS[s]];
    tokS[s] = (size_t)(ti < 0 ? 0 : ti);
  }

#pragma unroll 1
  for (int kt = 0; kt < 8; ++kt) {
    const int kb = kt * 128;  // byte offset within 1024-B token row
#pragma unroll
    for (int s = 0; s < 4; ++s) {
      GLL16(Ab + tokS[s] * 1024 + kb + colS[s], (char*)As + wid * 1024 + s * 4096);
      GLL16(Bgb + (size_t)(tileN + rowS[s]) * 1024 + kb + colS[s],
            (char*)Bgs + wid * 1024 + s * 4096);
      GLL16(Bub + (size_t)(tileN + rowS[s]) * 1024 + kb + colS[s],
            (char*)Bus + wid * 1024 + s * 4096);
    }
    __syncthreads();

#pragma unroll
    for (int kk = 0; kk < 2; ++kk) {
      short8 a[4], bg[4], bu[4];
#pragma unroll
      for (int i = 0; i < 4; ++i) {
        int row = wr * 64 + i * 16 + r;
        int pc = (kk * 4 + kq) ^ (row & 7);
        a[i] = *(const short8*)&As[row * 64 + pc * 8];
      }
#pragma unroll
      for (int j = 0; j < 4; ++j) {
        int row = wcol * 64 + j * 16 + r;
        int pc = (kk * 4 + kq) ^ (row & 7);
        bg[j] = *(const short8*)&Bgs[row * 64 + pc * 8];
        bu[j] = *(const short8*)&Bus[row * 64 + pc * 8];
      }
#pragma unroll
      for (int i = 0; i < 4; ++i)
#pragma unroll
        for (int j = 0; j < 4; ++j) {
          accg[i][j] = __builtin_amdgcn_mfma_f32_16x16x32_bf16(a[i], bg[j], accg[i][j], 0, 0, 0);
          accu[i][j] = __builtin_amdgcn_mfma_f32_16x16x32_bf16(a[i], bu[j], accu[i][j], 0, 0, 0);
        }
    }
    __syncthreads();
  }

  // ---- LDS-transpose epilogue (bf16) staged entirely within the dead As
  // region: [32][136] bf16 = 8.7 KB <= 16 KB. 4 batches of 32 rows; then each
  // thread stores 16 contiguous bf16 (2 x short8 = 32 B) per batch.
  __hip_bfloat16* Csb = (__hip_bfloat16*)&As[0];
  const int rowl = tid >> 3;           // 0..31
  const int cbase = (tid & 7) * 16;    // 0..112
#pragma unroll
  for (int batch = 0; batch < 4; ++batch) {
    __syncthreads();  // As free (K-loop done / prev batch consumed)
    if (wr == (batch >> 1)) {
      int bi0 = (batch & 1) * 2;
#pragma unroll
      for (int ii = 0; ii < 2; ++ii) {
        int i = bi0 + ii;
#pragma unroll
        for (int j = 0; j < 4; ++j) {
          int cl = wcol * 64 + j * 16 + r;
#pragma unroll
          for (int q = 0; q < 4; ++q) {
            int rl = ii * 16 + kq * 4 + q;
            float g = accg[i][j][q], u = accu[i][j][q];
            float val = g / (1.f + __expf(-g)) * u;
            Csb[rl * 136 + cl] = __float2bfloat16(val);
          }
        }
      }
    }
    __syncthreads();
    int row = tileBase + batch * 32 + rowl;
    __hip_bfloat16* gout = GU + (size_t)row * kFF + tileN + cbase;
    const __hip_bfloat16* crow = &Csb[rowl * 136 + cbase];
    *(short8*)(gout) = *(const short8*)(crow);
    *(short8*)(gout + 8) = *(const short8*)(crow + 8);
  }
}

// out[pairTok[row]] (=|+=) pairW[row] * (gu[row] @ Wdown[e]^T)  — no atomics.
__global__ __launch_bounds__(256, 2) void k_down_sp(const __hip_bfloat16* __restrict__ GU,
                                                    const __hip_bfloat16* __restrict__ Wd0,
                                                    const int* __restrict__ pairTok,
                                                    const float* __restrict__ pairW,
                                                    const int* __restrict__ tileExpert,
                                                    float* __restrict__ out,
                                                    float* __restrict__ dump,
                                                    int tileOff, int first) {
  const int tile = tileOff + (blockIdx.x >> 2);
  const int e = tileExpert[tile];
  if (e < 0) return;
  __shared__ __hip_bfloat16 As[128 * 64];
  __shared__ __hip_bfloat16 Bs[128 * 64];
  __shared__ float Cs[32 * 132];  // dedicated epilogue staging (16.9 KB)
  const int tid = threadIdx.x;
  const int wid = tid >> 6, lane = tid & 63;
  const int tileBase = tile * 128, tileN = (blockIdx.x & 3) * 128;
  const int wr = wid >> 1, wcol = wid & 1;
  const int r = lane & 15, kq = lane >> 4;

  f32x4 acc[4][4] = {};

  const char* Ab = (const char*)GU;
  const char* Bb = (const char*)(Wd0 + (size_t)e * kH * kFF);

  int rowS[4], colS[4];
#pragma unroll
  for (int s = 0; s < 4; ++s) {
    int off = wid * 1024 + lane * 16 + s * 4096;
    rowS[s] = off >> 7;
    int p = (off & 127) >> 4;
    colS[s] = ((p ^ (rowS[s] & 7)) << 4);
  }

#pragma unroll 1
  for (int kt = 0; kt < 8; ++kt) {
    const int kb = kt * 128;
#pragma unroll
    for (int s = 0; s < 4; ++s) {
      GLL16(Ab + (size_t)(tileBase + rowS[s]) * 1024 + kb + colS[s],
            (char*)As + wid * 1024 + s * 4096);
      GLL16(Bb + (size_t)(tileN + rowS[s]) * 1024 + kb + colS[s],
            (char*)Bs + wid * 1024 + s * 4096);
    }
    __syncthreads();

#pragma unroll
    for (int kk = 0; kk < 2; ++kk) {
      short8 a[4], b[4];
#pragma unroll
      for (int i = 0; i < 4; ++i) {
        int row = wr * 64 + i * 16 + r;
        int pc = (kk * 4 + kq) ^ (row & 7);
        a[i] = *(const short8*)&As[row * 64 + pc * 8];
      }
#pragma unroll
      for (int j = 0; j < 4; ++j) {
        int row = wcol * 64 + j * 16 + r;
        int pc = (kk * 4 + kq) ^ (row & 7);
        b[j] = *(const short8*)&Bs[row * 64 + pc * 8];
      }
#pragma unroll
      for (int i = 0; i < 4; ++i)
#pragma unroll
        for (int j = 0; j < 4; ++j)
          acc[i][j] = __builtin_amdgcn_mfma_f32_16x16x32_bf16(a[i], b[j], acc[i][j], 0, 0, 0);
    }
    __syncthreads();
  }

  // ---- LDS-transpose epilogue: 4 batches of 32 rows through dedicated Cs
  const int rowl = tid >> 3;            // 0..31
  const int cbase = (tid & 7) * 16;     // 0..112, f32 col within 128
#pragma unroll
  for (int batch = 0; batch < 4; ++batch) {
    __syncthreads();
    if (wr == (batch >> 1)) {
      int bi0 = (batch & 1) * 2;
#pragma unroll
      for (int ii = 0; ii < 2; ++ii) {
        int i = bi0 + ii;
#pragma unroll
        for (int j = 0; j < 4; ++j) {
          int cl = wcol * 64 + j * 16 + r;
#pragma unroll
          for (int q = 0; q < 4; ++q) {
            int rl = ii * 16 + kq * 4 + q;
            Cs[rl * 132 + cl] = acc[i][j][q];
          }
        }
      }
    }
    __syncthreads();
    int prow = tileBase + batch * 32 + rowl;
    float wv = pairW[prow];
    int tk = pairTok[prow];
    float* orow = (tk >= 0) ? out + (size_t)tk * kH + tileN + cbase
                            : dump + (size_t)(prow & 127) * kH + tileN + cbase;
    const float* crow = &Cs[rowl * 132 + cbase];
#pragma unroll
    for (int c = 0; c < 4; ++c) {
      f32x4 v = *(const f32x4*)(crow + c * 4);
      v *= wv;
      if (first) {
        *(f32x4*)(orow + c * 4) = v;
      } else {
        f32x4 o = *(const f32x4*)(orow + c * 4);
        *(f32x4*)(orow + c * 4) = o + v;
      }
    }
  }
}

// ---------------- launcher ----------------
extern "C" void kernel_launch(void* const* d_in, const int* in_sizes, int n_in,
                              void* d_out, int out_size, void* d_ws, size_t ws_size,
                              hipStream_t stream) {
  const float* x = (const float*)d_in[0];
  const float* Wp = (const float*)d_in[1];
  const float* bp = (const float*)d_in[2];
  const float* Wg = (const float*)d_in[3];
  const float* Wgate = (const float*)d_in[4];
  const float* Wup = (const float*)d_in[5];
  const float* Wdown = (const float*)d_in[6];
  float* out = (float*)d_out;

  char* ws = (char*)d_ws;
  __hip_bfloat16* tok = (__hip_bfloat16*)(ws + OFF_TOK);
  __hip_bfloat16* gu = (__hip_bfloat16*)(ws + OFF_GU);
  int* topi = (int*)(ws + OFF_TOPI);
  float* topw = (float*)(ws + OFF_TOPW);
  int* chunkCnt = (int*)(ws + OFF_CCNT);
  int* chunkOff = (int*)(ws + OFF_COFF);
  int* eoff = (int*)(ws + OFF_EOFF);
  int* tileExpert = (int*)(ws + OFF_TILE);
  int* pairTok = (int*)(ws + OFF_PTOK);
  float* pairW = (float*)(ws + OFF_PW);
  float* dump = (float*)(ws + OFF_DUMP);
  __hip_bfloat16* bgw = (__hip_bfloat16*)(ws + OFF_BG);
  __hip_bfloat16* buw = (__hip_bfloat16*)(ws + OFF_BU);
  __hip_bfloat16* bdw = (__hip_bfloat16*)(ws + OFF_BD);
  double* wc = (double*)(ws + OFF_WC);
  double* bcv = (double*)(ws + OFF_BC);

  const int nw = kE * kFF * kH;
  k_conv3<<<3072, 256, 0, stream>>>(Wgate, Wup, Wdown, bgw, buw, bdw, nw);
  k_wcomb<<<1, 128, 0, stream>>>(Wg, Wp, bp, wc, bcv);
  k_patch<<<8192, 256, 0, stream>>>(x, Wp, bp, tok);
  k_router<<<256, 256, 0, stream>>>(x, wc, bcv, topi, topw, chunkCnt);
  k_scan<<<1, 256, 0, stream>>>(chunkCnt, chunkOff, eoff, tileExpert, pairTok, pairW);
  k_fill<<<256, 256, 0, stream>>>(topi, topw, chunkOff, eoff, pairTok, pairW);

  k_gateup_sp<<<kMaxTiles * 4, 256, 0, stream>>>(tok, bgw, buw, pairTok, tileExpert, gu);
  k_down_sp<<<kTilesPerSlot * 4, 256, 0, stream>>>(gu, bdw, pairTok, pairW, tileExpert, out,
                                                   dump, 0, 1);
  k_down_sp<<<kTilesPerSlot * 4, 256, 0, stream>>>(gu, bdw, pairTok, pairW, tileExpert, out,
                                                   dump, kTilesPerSlot, 0);
}

// Round 13
// 464.901 us; speedup vs baseline: 1.7789x; 1.1177x over previous
//
#include <hip/hip_runtime.h>
#include <hip/hip_bf16.h>
#include <cstdint>
#include <cstddef>

typedef __attribute__((ext_vector_type(8))) short short8;
typedef __attribute__((ext_vector_type(4))) float f32x4;

#define GLL16(g, l) __builtin_amdgcn_global_load_lds(                         \
    (const __attribute__((address_space(1))) void*)(g),                        \
    (__attribute__((address_space(3))) void*)(l), 16, 0, 0)

constexpr int kB = 32, kC = 64, kL = 512;
constexpr int kPL = 16, kPN = 32;
constexpr int kH = 512, kFF = 512, kE = 8;
constexpr int kT = kB * kC * kPN;              // 65536 tokens
constexpr int kTilesPerSlot = 520;             // 512 + 8 pad tiles (fixed region)
constexpr int kMaxTiles = 2 * kTilesPerSlot;   // 1040
constexpr int kMaxPairs = kMaxTiles * 128;     // 133120

// ---------------- workspace layout (bytes) ----------------
constexpr size_t OFF_TOK  = 0;                                    // T*H bf16 = 64 MiB
constexpr size_t OFF_GU   = OFF_TOK + (size_t)kT * kH * 2;        // pairs*FF bf16
constexpr size_t OFF_TOPI = OFF_GU + (size_t)kMaxPairs * kFF * 2; // T int
constexpr size_t OFF_TOPW = OFF_TOPI + (size_t)kT * 4;            // T*2 float
constexpr size_t OFF_CCNT = OFF_TOPW + (size_t)kT * 8;            // 256*16 int
constexpr size_t OFF_COFF = OFF_CCNT + 256 * 16 * 4;              // 256*16 int
constexpr size_t OFF_EOFF = OFF_COFF + 256 * 16 * 4;              // 16 int (+pad)
constexpr size_t OFF_TILE = OFF_EOFF + 256;                       // kMaxTiles int
constexpr size_t OFF_PTOK = OFF_TILE + ((kMaxTiles * 4 + 255) & ~255ull);
constexpr size_t OFF_PW   = OFF_PTOK + (size_t)kMaxPairs * 4;
constexpr size_t OFF_DUMP = OFF_PW + (size_t)kMaxPairs * 4;       // 128*512 f32
constexpr size_t OFF_BG   = OFF_DUMP + 128 * 512 * 4;             // E*FF*H bf16
constexpr size_t OFF_BU   = OFF_BG + (size_t)kE * kFF * kH * 2;
constexpr size_t OFF_BD   = OFF_BU + (size_t)kE * kFF * kH * 2;
constexpr size_t OFF_WC   = OFF_BD + (size_t)kE * kH * kFF * 2;   // 8*16 double
constexpr size_t OFF_BC   = OFF_WC + 8 * 16 * 8;                  // 8 double

// ---------------- small kernels ----------------
__global__ __launch_bounds__(256) void k_conv3(const float* __restrict__ a,
                                               const float* __restrict__ b,
                                               const float* __restrict__ c,
                                               __hip_bfloat16* __restrict__ da,
                                               __hip_bfloat16* __restrict__ db,
                                               __hip_bfloat16* __restrict__ dc, int n) {
  for (int i = blockIdx.x * blockDim.x + threadIdx.x; i < 3 * n; i += gridDim.x * blockDim.x) {
    int reg = i / n, j = i - reg * n;
    const float* s = (reg == 0) ? a : (reg == 1) ? b : c;
    __hip_bfloat16* d = (reg == 0) ? da : (reg == 1) ? db : dc;
    d[j] = __float2bfloat16(s[j]);
  }
}

// Wcomb[e][l] = sum_d Wg[e][d]*Wp[d][l] (fp64); bconst[e] = sum_d bp[d]*Wg[e][d]
// r13: operands staged in LDS (coalesced global reads; same fp64 order/values).
__global__ __launch_bounds__(256) void k_wcomb(const float* __restrict__ Wg,
                                               const float* __restrict__ Wp,
                                               const float* __restrict__ bp,
                                               double* __restrict__ wc,
                                               double* __restrict__ bc) {
  __shared__ float sWg[8 * 512];    // 16 KB
  __shared__ float sWp[512 * 16];   // 32 KB
  __shared__ float sbp[512];
  int tid = threadIdx.x;
  for (int i = tid; i < 8 * 512; i += 256) sWg[i] = Wg[i];
  for (int i = tid; i < 512 * 16; i += 256) sWp[i] = Wp[i];
  for (int i = tid; i < 512; i += 256) sbp[i] = bp[i];
  __syncthreads();
  if (tid < 128) {
    int e = tid >> 4, l = tid & 15;
    double s = 0.0;
    for (int d = 0; d < kH; ++d) s += (double)sWg[e * kH + d] * (double)sWp[d * kPL + l];
    wc[e * kPL + l] = s;
    if (l == 0) {
      double b = 0.0;
      for (int d = 0; d < kH; ++d) b += (double)sWg[e * kH + d] * (double)sbp[d];
      bc[e] = b;
    }
  }
}

// patchify + project: tok[t][d] = bf16( sum_l x[bc, p*16+l]*Wp[d][l] + bp[d] )
__global__ __launch_bounds__(256) void k_patch(const float* __restrict__ x,
                                               const float* __restrict__ Wp,
                                               const float* __restrict__ bp,
                                               __hip_bfloat16* __restrict__ tok) {
  __shared__ float sWp[512 * 17];
  __shared__ float sx[128];
  __shared__ float sbp[512];
  int bb = blockIdx.x;            // 8192 blocks
  int bc = bb >> 2, pg = bb & 3;
  int tid = threadIdx.x;
  for (int i = tid; i < 512 * 16; i += 256) sWp[(i >> 4) * 17 + (i & 15)] = Wp[i];
  if (tid < 128) sx[tid] = x[(size_t)bc * 512 + pg * 128 + tid];
  for (int i = tid; i < 512; i += 256) sbp[i] = bp[i];
  __syncthreads();
  for (int tl = 0; tl < 8; ++tl) {
    int t = bc * kPN + pg * 8 + tl;
    const float* xp = &sx[tl * 16];
    for (int d = tid; d < 512; d += 256) {
      float s = sbp[d];
#pragma unroll
      for (int l = 0; l < 16; ++l) s += xp[l] * sWp[d * 17 + l];
      tok[(size_t)t * kH + d] = __float2bfloat16(s);
    }
  }
}

// router: fp64 logits via fused (Wp^T Wg), fp64 softmax, top-2.
__global__ __launch_bounds__(256) void k_router(const float* __restrict__ x,
                                                const double* __restrict__ wc,
                                                const double* __restrict__ bc,
                                                int* __restrict__ topi,
                                                float* __restrict__ topw,
                                                int* __restrict__ chunkCnt) {
  int t = blockIdx.x * 256 + threadIdx.x;
  int bci = t >> 5, p = t & 31;
  const float* xp = &x[(size_t)bci * 512 + p * 16];
  double xl[16];
#pragma unroll
  for (int l = 0; l < 16; ++l) xl[l] = (double)xp[l];
  double lo[8];
  double m = -1e300;
#pragma unroll
  for (int e = 0; e < 8; ++e) {
    double s = bc[e];
#pragma unroll
    for (int l = 0; l < 16; ++l) s += xl[l] * wc[e * 16 + l];
    lo[e] = s;
    m = fmax(m, s);
  }
  double den = 0.0;
#pragma unroll
  for (int e = 0; e < 8; ++e) {
    lo[e] = exp(lo[e] - m);
    den += lo[e];
  }
  int i1 = 0;
  double v1 = lo[0];
#pragma unroll
  for (int e = 1; e < 8; ++e)
    if (lo[e] > v1) { v1 = lo[e]; i1 = e; }
  int i2 = -1;
  double v2 = -1.0;
#pragma unroll
  for (int e = 0; e < 8; ++e)
    if (e != i1 && lo[e] > v2) { v2 = lo[e]; i2 = e; }
  topi[t] = i1 | (i2 << 4);
  topw[2 * t] = (float)(v1 / den);
  topw[2 * t + 1] = (float)(v2 / den);

  __shared__ int wsum[16][4];
  int wave = threadIdx.x >> 6, lane = threadIdx.x & 63;
#pragma unroll
  for (int seg = 0; seg < 16; ++seg) {
    int e = seg & 7;
    bool sel = (seg < 8) ? (i1 == e) : (i2 == e);
    unsigned long long mm = __ballot(sel);
    if (lane == 0) wsum[seg][wave] = __popcll(mm);
  }
  __syncthreads();
  if (threadIdx.x < 16)
    chunkCnt[blockIdx.x * 16 + threadIdx.x] =
        wsum[threadIdx.x][0] + wsum[threadIdx.x][1] + wsum[threadIdx.x][2] + wsum[threadIdx.x][3];
}

// scan: per-segment chunk offsets (LDS-staged), segment bases, tile table, pad fill
__global__ __launch_bounds__(256) void k_scan(const int* __restrict__ chunkCnt,
                                              int* __restrict__ chunkOff,
                                              int* __restrict__ eoff,
                                              int* __restrict__ tileExpert,
                                              int* __restrict__ pairTok,
                                              float* __restrict__ pairW) {
  int tid = threadIdx.x;
  __shared__ int cnt[256 * 16];
  __shared__ int coff[256 * 16];
  for (int i = tid; i < 256 * 16; i += 256) cnt[i] = chunkCnt[i];
  __syncthreads();
  __shared__ int totals[16];
  __shared__ int base[16];
  __shared__ int padded[16];
  if (tid < 16) {
    int run = 0;
    for (int c = 0; c < 256; ++c) {
      coff[c * 16 + tid] = run;
      run += cnt[c * 16 + tid];
    }
    totals[tid] = run;
  }
  __syncthreads();
  for (int i = tid; i < 256 * 16; i += 256) chunkOff[i] = coff[i];
  if (tid == 0) {
    for (int s = 0; s < 2; ++s) {
      int b = s * kTilesPerSlot * 128;
      for (int e = 0; e < 8; ++e) {
        int seg = s * 8 + e;
        base[seg] = b;
        padded[seg] = (totals[seg] + 127) & ~127;
        b += padded[seg];
      }
    }
  }
  __syncthreads();
  if (tid < 16) eoff[tid] = base[tid];
  for (int tI = tid; tI < kMaxTiles; tI += 256) tileExpert[tI] = -1;
  __syncthreads();
  for (int seg = 0; seg < 16; ++seg) {
    int e = seg & 7;
    int tile0 = base[seg] >> 7, nt = padded[seg] >> 7;
    for (int tI = tid; tI < nt; tI += 256) tileExpert[tile0 + tI] = e;
    for (int p = base[seg] + totals[seg] + tid; p < base[seg] + padded[seg]; p += 256) {
      pairTok[p] = -1;  // pad sentinel
      pairW[p] = 0.f;
    }
  }
}

// fill: deterministic token-ordered compaction into per-(slot,expert) segments
__global__ __launch_bounds__(256) void k_fill(const int* __restrict__ topi,
                                              const float* __restrict__ topw,
                                              const int* __restrict__ chunkOff,
                                              const int* __restrict__ eoff,
                                              int* __restrict__ pairTok,
                                              float* __restrict__ pairW) {
  int chunk = blockIdx.x;
  int t = chunk * 256 + threadIdx.x;
  int pk = topi[t];
  int i1 = pk & 15, i2 = (pk >> 4) & 15;
  float w1 = topw[2 * t], w2 = topw[2 * t + 1];
  int wave = threadIdx.x >> 6, lane = threadIdx.x & 63;
  __shared__ int wsum[16][4];
  int pre[16];
  bool sel[16];
#pragma unroll
  for (int seg = 0; seg < 16; ++seg) {
    int e = seg & 7;
    sel[seg] = (seg < 8) ? (i1 == e) : (i2 == e);
    unsigned long long mm = __ballot(sel[seg]);
    pre[seg] = __popcll(mm & ((1ull << lane) - 1));
    if (lane == 0) wsum[seg][wave] = __popcll(mm);
  }
  __syncthreads();
#pragma unroll
  for (int seg = 0; seg < 16; ++seg) {
    if (!sel[seg]) continue;
    int woff = 0;
    for (int w = 0; w < wave; ++w) woff += wsum[seg][w];
    int pos = eoff[seg] + chunkOff[chunk * 16 + seg] + woff + pre[seg];
    pairTok[pos] = t;
    pairW[pos] = (seg < 8) ? w1 : w2;
  }
}

// ---------------- sparse GEMM kernels (128x128xBK=64 bf16 MFMA) ----------------
// BK=64 single-buffer (r10 win): one barrier pair per 64 MFMA/wave.
// 8-chunk XOR swizzle: physical chunk p at row holds logical p ^ (row&7).
// N-block-fastest grid (r6). launch_bounds (256,2) — (256,3) spills (r11:
// accg+accu = 128 acc regs + ~112 arch > 170 cap).
// r13: gateup epilogue REVERTED to r10 direct stores (r12's staged epilogue
// cost +30 µs: +8 barriers, half-wave serialization, 529K bank conflicts).
// Down keeps its staged f32 epilogue (r9 win — scatter-by-token is the
// pathological case; gateup's dense rows are not).

// gu[pairRow][col] = silu(tok[pairTok[row]] @ Wgate[e]^T) * (tok[...] @ Wup[e]^T)
__global__ __launch_bounds__(256, 2) void k_gateup_sp(const __hip_bfloat16* __restrict__ tok,
                                                      const __hip_bfloat16* __restrict__ Wg0,
                                                      const __hip_bfloat16* __restrict__ Wu0,
                                                      const int* __restrict__ pairTok,
                                                      const int* __restrict__ tileExpert,
                                                      __hip_bfloat16* __restrict__ GU) {
  const int tileIdx = blockIdx.x >> 2;
  const int e = tileExpert[tileIdx];
  if (e < 0) return;
  __shared__ __hip_bfloat16 As[128 * 64];   // 16 KB each
  __shared__ __hip_bfloat16 Bgs[128 * 64];
  __shared__ __hip_bfloat16 Bus[128 * 64];
  const int tid = threadIdx.x;
  const int wid = tid >> 6, lane = tid & 63;
  const int tileBase = tileIdx * 128, tileN = (blockIdx.x & 3) * 128;
  const int wr = wid >> 1, wcol = wid & 1;
  const int r = lane & 15, kq = lane >> 4;

  f32x4 accg[4][4] = {};
  f32x4 accu[4][4] = {};

  const char* Ab = (const char*)tok;
  const char* Bgb = (const char*)(Wg0 + (size_t)e * kFF * kH);
  const char* Bub = (const char*)(Wu0 + (size_t)e * kFF * kH);

  int rowS[4], colS[4];
  size_t tokS[4];
#pragma unroll
  for (int s = 0; s < 4; ++s) {
    int off = wid * 1024 + lane * 16 + s * 4096;
    rowS[s] = off >> 7;                         // 128-B rows
    int p = (off & 127) >> 4;                   // physical chunk 0..7
    colS[s] = ((p ^ (rowS[s] & 7)) << 4);       // pre-swizzled global col (bytes)
    int ti = pairTok[tileBase + rowS[s]];
    tokS[s] = (size_t)(ti < 0 ? 0 : ti);
  }

#pragma unroll 1
  for (int kt = 0; kt < 8; ++kt) {
    const int kb = kt * 128;  // byte offset within 1024-B token row
#pragma unroll
    for (int s = 0; s < 4; ++s) {
      GLL16(Ab + tokS[s] * 1024 + kb + colS[s], (char*)As + wid * 1024 + s * 4096);
      GLL16(Bgb + (size_t)(tileN + rowS[s]) * 1024 + kb + colS[s],
            (char*)Bgs + wid * 1024 + s * 4096);
      GLL16(Bub + (size_t)(tileN + rowS[s]) * 1024 + kb + colS[s],
            (char*)Bus + wid * 1024 + s * 4096);
    }
    __syncthreads();

#pragma unroll
    for (int kk = 0; kk < 2; ++kk) {
      short8 a[4], bg[4], bu[4];
#pragma unroll
      for (int i = 0; i < 4; ++i) {
        int row = wr * 64 + i * 16 + r;
        int pc = (kk * 4 + kq) ^ (row & 7);
        a[i] = *(const short8*)&As[row * 64 + pc * 8];
      }
#pragma unroll
      for (int j = 0; j < 4; ++j) {
        int row = wcol * 64 + j * 16 + r;
        int pc = (kk * 4 + kq) ^ (row & 7);
        bg[j] = *(const short8*)&Bgs[row * 64 + pc * 8];
        bu[j] = *(const short8*)&Bus[row * 64 + pc * 8];
      }
#pragma unroll
      for (int i = 0; i < 4; ++i)
#pragma unroll
        for (int j = 0; j < 4; ++j) {
          accg[i][j] = __builtin_amdgcn_mfma_f32_16x16x32_bf16(a[i], bg[j], accg[i][j], 0, 0, 0);
          accu[i][j] = __builtin_amdgcn_mfma_f32_16x16x32_bf16(a[i], bu[j], accu[i][j], 0, 0, 0);
        }
    }
    __syncthreads();
  }

  // direct-store epilogue (r10-proven)
#pragma unroll
  for (int i = 0; i < 4; ++i)
#pragma unroll
    for (int j = 0; j < 4; ++j)
#pragma unroll
      for (int q = 0; q < 4; ++q) {
        int row = tileBase + wr * 64 + i * 16 + kq * 4 + q;
        int col = tileN + wcol * 64 + j * 16 + r;
        float g = accg[i][j][q], u = accu[i][j][q];
        float val = g / (1.f + __expf(-g)) * u;
        GU[(size_t)row * kFF + col] = __float2bfloat16(val);
      }
}

// out[pairTok[row]] (=|+=) pairW[row] * (gu[row] @ Wdown[e]^T)  — no atomics.
__global__ __launch_bounds__(256, 2) void k_down_sp(const __hip_bfloat16* __restrict__ GU,
                                                    const __hip_bfloat16* __restrict__ Wd0,
                                                    const int* __restrict__ pairTok,
                                                    const float* __restrict__ pairW,
                                                    const int* __restrict__ tileExpert,
                                                    float* __restrict__ out,
                                                    float* __restrict__ dump,
                                                    int tileOff, int first) {
  const int tile = tileOff + (blockIdx.x >> 2);
  const int e = tileExpert[tile];
  if (e < 0) return;
  __shared__ __hip_bfloat16 As[128 * 64];
  __shared__ __hip_bfloat16 Bs[128 * 64];
  __shared__ float Cs[32 * 132];  // dedicated epilogue staging (16.9 KB)
  const int tid = threadIdx.x;
  const int wid = tid >> 6, lane = tid & 63;
  const int tileBase = tile * 128, tileN = (blockIdx.x & 3) * 128;
  const int wr = wid >> 1, wcol = wid & 1;
  const int r = lane & 15, kq = lane >> 4;

  f32x4 acc[4][4] = {};

  const char* Ab = (const char*)GU;
  const char* Bb = (const char*)(Wd0 + (size_t)e * kH * kFF);

  int rowS[4], colS[4];
#pragma unroll
  for (int s = 0; s < 4; ++s) {
    int off = wid * 1024 + lane * 16 + s * 4096;
    rowS[s] = off >> 7;
    int p = (off & 127) >> 4;
    colS[s] = ((p ^ (rowS[s] & 7)) << 4);
  }

#pragma unroll 1
  for (int kt = 0; kt < 8; ++kt) {
    const int kb = kt * 128;
#pragma unroll
    for (int s = 0; s < 4; ++s) {
      GLL16(Ab + (size_t)(tileBase + rowS[s]) * 1024 + kb + colS[s],
            (char*)As + wid * 1024 + s * 4096);
      GLL16(Bb + (size_t)(tileN + rowS[s]) * 1024 + kb + colS[s],
            (char*)Bs + wid * 1024 + s * 4096);
    }
    __syncthreads();

#pragma unroll
    for (int kk = 0; kk < 2; ++kk) {
      short8 a[4], b[4];
#pragma unroll
      for (int i = 0; i < 4; ++i) {
        int row = wr * 64 + i * 16 + r;
        int pc = (kk * 4 + kq) ^ (row & 7);
        a[i] = *(const short8*)&As[row * 64 + pc * 8];
      }
#pragma unroll
      for (int j = 0; j < 4; ++j) {
        int row = wcol * 64 + j * 16 + r;
        int pc = (kk * 4 + kq) ^ (row & 7);
        b[j] = *(const short8*)&Bs[row * 64 + pc * 8];
      }
#pragma unroll
      for (int i = 0; i < 4; ++i)
#pragma unroll
        for (int j = 0; j < 4; ++j)
          acc[i][j] = __builtin_amdgcn_mfma_f32_16x16x32_bf16(a[i], b[j], acc[i][j], 0, 0, 0);
    }
    __syncthreads();
  }

  // ---- LDS-transpose epilogue: 4 batches of 32 rows through dedicated Cs
  const int rowl = tid >> 3;            // 0..31
  const int cbase = (tid & 7) * 16;     // 0..112, f32 col within 128
#pragma unroll
  for (int batch = 0; batch < 4; ++batch) {
    __syncthreads();
    if (wr == (batch >> 1)) {
      int bi0 = (batch & 1) * 2;
#pragma unroll
      for (int ii = 0; ii < 2; ++ii) {
        int i = bi0 + ii;
#pragma unroll
        for (int j = 0; j < 4; ++j) {
          int cl = wcol * 64 + j * 16 + r;
#pragma unroll
          for (int q = 0; q < 4; ++q) {
            int rl = ii * 16 + kq * 4 + q;
            Cs[rl * 132 + cl] = acc[i][j][q];
          }
        }
      }
    }
    __syncthreads();
    int prow = tileBase + batch * 32 + rowl;
    float wv = pairW[prow];
    int tk = pairTok[prow];
    float* orow = (tk >= 0) ? out + (size_t)tk * kH + tileN + cbase
                            : dump + (size_t)(prow & 127) * kH + tileN + cbase;
    const float* crow = &Cs[rowl * 132 + cbase];
#pragma unroll
    for (int c = 0; c < 4; ++c) {
      f32x4 v = *(const f32x4*)(crow + c * 4);
      v *= wv;
      if (first) {
        *(f32x4*)(orow + c * 4) = v;
      } else {
        f32x4 o = *(const f32x4*)(orow + c * 4);
        *(f32x4*)(orow + c * 4) = o + v;
      }
    }
  }
}

// ---------------- launcher ----------------
extern "C" void kernel_launch(void* const* d_in, const int* in_sizes, int n_in,
                              void* d_out, int out_size, void* d_ws, size_t ws_size,
                              hipStream_t stream) {
  const float* x = (const float*)d_in[0];
  const float* Wp = (const float*)d_in[1];
  const float* bp = (const float*)d_in[2];
  const float* Wg = (const float*)d_in[3];
  const float* Wgate = (const float*)d_in[4];
  const float* Wup = (const float*)d_in[5];
  const float* Wdown = (const float*)d_in[6];
  float* out = (float*)d_out;

  char* ws = (char*)d_ws;
  __hip_bfloat16* tok = (__hip_bfloat16*)(ws + OFF_TOK);
  __hip_bfloat16* gu = (__hip_bfloat16*)(ws + OFF_GU);
  int* topi = (int*)(ws + OFF_TOPI);
  float* topw = (float*)(ws + OFF_TOPW);
  int* chunkCnt = (int*)(ws + OFF_CCNT);
  int* chunkOff = (int*)(ws + OFF_COFF);
  int* eoff = (int*)(ws + OFF_EOFF);
  int* tileExpert = (int*)(ws + OFF_TILE);
  int* pairTok = (int*)(ws + OFF_PTOK);
  float* pairW = (float*)(ws + OFF_PW);
  float* dump = (float*)(ws + OFF_DUMP);
  __hip_bfloat16* bgw = (__hip_bfloat16*)(ws + OFF_BG);
  __hip_bfloat16* buw = (__hip_bfloat16*)(ws + OFF_BU);
  __hip_bfloat16* bdw = (__hip_bfloat16*)(ws + OFF_BD);
  double* wc = (double*)(ws + OFF_WC);
  double* bcv = (double*)(ws + OFF_BC);

  const int nw = kE * kFF * kH;
  k_conv3<<<3072, 256, 0, stream>>>(Wgate, Wup, Wdown, bgw, buw, bdw, nw);
  k_wcomb<<<1, 256, 0, stream>>>(Wg, Wp, bp, wc, bcv);
  k_patch<<<8192, 256, 0, stream>>>(x, Wp, bp, tok);
  k_router<<<256, 256, 0, stream>>>(x, wc, bcv, topi, topw, chunkCnt);
  k_scan<<<1, 256, 0, stream>>>(chunkCnt, chunkOff, eoff, tileExpert, pairTok, pairW);
  k_fill<<<256, 256, 0, stream>>>(topi, topw, chunkOff, eoff, pairTok, pairW);

  k_gateup_sp<<<kMaxTiles * 4, 256, 0, stream>>>(tok, bgw, buw, pairTok, tileExpert, gu);
  k_down_sp<<<kTilesPerSlot * 4, 256, 0, stream>>>(gu, bdw, pairTok, pairW, tileExpert, out,
                                                   dump, 0, 1);
  k_down_sp<<<kTilesPerSlot * 4, 256, 0, stream>>>(gu, bdw, pairTok, pairW, tileExpert, out,
                                                   dump, kTilesPerSlot, 0);
}

// Round 14
// 455.754 us; speedup vs baseline: 1.8146x; 1.0201x over previous
//
#include <hip/hip_runtime.h>
#include <hip/hip_bf16.h>
#include <cstdint>
#include <cstddef>

typedef __attribute__((ext_vector_type(8))) short short8;
typedef __attribute__((ext_vector_type(4))) short short4v;
typedef __attribute__((ext_vector_type(4))) float f32x4;

#define GLL16(g, l) __builtin_amdgcn_global_load_lds(                         \
    (const __attribute__((address_space(1))) void*)(g),                        \
    (__attribute__((address_space(3))) void*)(l), 16, 0, 0)

constexpr int kB = 32, kC = 64, kL = 512;
constexpr int kPL = 16, kPN = 32;
constexpr int kH = 512, kFF = 512, kE = 8;
constexpr int kT = kB * kC * kPN;              // 65536 tokens
constexpr int kTilesPerSlot = 520;             // 512 + 8 pad tiles (fixed region)
constexpr int kMaxTiles = 2 * kTilesPerSlot;   // 1040
constexpr int kMaxPairs = kMaxTiles * 128;     // 133120

// ---------------- workspace layout (bytes) ----------------
constexpr size_t OFF_TOK  = 0;                                    // T*H bf16 = 64 MiB
constexpr size_t OFF_GU   = OFF_TOK + (size_t)kT * kH * 2;        // pairs*FF bf16
constexpr size_t OFF_TOPI = OFF_GU + (size_t)kMaxPairs * kFF * 2; // T int
constexpr size_t OFF_TOPW = OFF_TOPI + (size_t)kT * 4;            // T*2 float
constexpr size_t OFF_CCNT = OFF_TOPW + (size_t)kT * 8;            // 256*16 int
constexpr size_t OFF_COFF = OFF_CCNT + 256 * 16 * 4;              // 256*16 int
constexpr size_t OFF_EOFF = OFF_COFF + 256 * 16 * 4;              // 16 int (+pad)
constexpr size_t OFF_TILE = OFF_EOFF + 256;                       // kMaxTiles int
constexpr size_t OFF_PTOK = OFF_TILE + ((kMaxTiles * 4 + 255) & ~255ull);
constexpr size_t OFF_PW   = OFF_PTOK + (size_t)kMaxPairs * 4;
constexpr size_t OFF_DUMP = OFF_PW + (size_t)kMaxPairs * 4;       // 128*512 f32
constexpr size_t OFF_BG   = OFF_DUMP + 128 * 512 * 4;             // E*FF*H bf16
constexpr size_t OFF_BU   = OFF_BG + (size_t)kE * kFF * kH * 2;
constexpr size_t OFF_BD   = OFF_BU + (size_t)kE * kFF * kH * 2;
constexpr size_t OFF_WC   = OFF_BD + (size_t)kE * kH * kFF * 2;   // 8*16 double
constexpr size_t OFF_BC   = OFF_WC + 8 * 16 * 8;                  // 8 double

// ---------------- small kernels ----------------
// r14: float4/short4 vectorized cast (G13)
__global__ __launch_bounds__(256) void k_conv3(const float* __restrict__ a,
                                               const float* __restrict__ b,
                                               const float* __restrict__ c,
                                               __hip_bfloat16* __restrict__ da,
                                               __hip_bfloat16* __restrict__ db,
                                               __hip_bfloat16* __restrict__ dc, int n) {
  const int n4 = n >> 2;
  for (int i = blockIdx.x * blockDim.x + threadIdx.x; i < 3 * n4;
       i += gridDim.x * blockDim.x) {
    int reg = i / n4, j = i - reg * n4;
    const float* s = (reg == 0) ? a : (reg == 1) ? b : c;
    __hip_bfloat16* d = (reg == 0) ? da : (reg == 1) ? db : dc;
    f32x4 v = ((const f32x4*)s)[j];
    __hip_bfloat16 tmp[4];
#pragma unroll
    for (int k = 0; k < 4; ++k) tmp[k] = __float2bfloat16(v[k]);
    ((short4v*)d)[j] = *(const short4v*)tmp;
  }
}

// Wcomb[e][l] = sum_d Wg[e][d]*Wp[d][l] (fp64); bconst[e] = sum_d bp[d]*Wg[e][d]
__global__ __launch_bounds__(256) void k_wcomb(const float* __restrict__ Wg,
                                               const float* __restrict__ Wp,
                                               const float* __restrict__ bp,
                                               double* __restrict__ wc,
                                               double* __restrict__ bc) {
  __shared__ float sWg[8 * 512];    // 16 KB
  __shared__ float sWp[512 * 16];   // 32 KB
  __shared__ float sbp[512];
  int tid = threadIdx.x;
  for (int i = tid; i < 8 * 512; i += 256) sWg[i] = Wg[i];
  for (int i = tid; i < 512 * 16; i += 256) sWp[i] = Wp[i];
  for (int i = tid; i < 512; i += 256) sbp[i] = bp[i];
  __syncthreads();
  if (tid < 128) {
    int e = tid >> 4, l = tid & 15;
    double s = 0.0;
    for (int d = 0; d < kH; ++d) s += (double)sWg[e * kH + d] * (double)sWp[d * kPL + l];
    wc[e * kPL + l] = s;
    if (l == 0) {
      double b = 0.0;
      for (int d = 0; d < kH; ++d) b += (double)sWg[e * kH + d] * (double)sbp[d];
      bc[e] = b;
    }
  }
}

// patchify + project: tok[t][d] = bf16( sum_l x[bc, p*16+l]*Wp[d][l] + bp[d] )
// r14: grid-stride over 4 tiles/block — Wp/bp staged ONCE per block (saves
// 3/4 of the Wp L2 re-reads + 6144 block dispatches). Compute mapping and
// f32 accumulation order unchanged (values bit-identical to r13).
__global__ __launch_bounds__(256) void k_patch(const float* __restrict__ x,
                                               const float* __restrict__ Wp,
                                               const float* __restrict__ bp,
                                               __hip_bfloat16* __restrict__ tok) {
  __shared__ float sWp[512 * 17];
  __shared__ float sx[128];
  __shared__ float sbp[512];
  int tid = threadIdx.x;
  for (int i = tid; i < 512 * 16; i += 256) sWp[(i >> 4) * 17 + (i & 15)] = Wp[i];
  for (int i = tid; i < 512; i += 256) sbp[i] = bp[i];
  for (int bb = blockIdx.x; bb < 8192; bb += gridDim.x) {
    int bc = bb >> 2, pg = bb & 3;
    __syncthreads();  // prev iteration's sx reads done (also covers sWp staging)
    if (tid < 128) sx[tid] = x[(size_t)bc * 512 + pg * 128 + tid];
    __syncthreads();
    for (int tl = 0; tl < 8; ++tl) {
      int t = bc * kPN + pg * 8 + tl;
      const float* xp = &sx[tl * 16];
      for (int d = tid; d < 512; d += 256) {
        float s = sbp[d];
#pragma unroll
        for (int l = 0; l < 16; ++l) s += xp[l] * sWp[d * 17 + l];
        tok[(size_t)t * kH + d] = __float2bfloat16(s);
      }
    }
  }
}

// router: fp64 logits via fused (Wp^T Wg), fp64 softmax, top-2.
__global__ __launch_bounds__(256) void k_router(const float* __restrict__ x,
                                                const double* __restrict__ wc,
                                                const double* __restrict__ bc,
                                                int* __restrict__ topi,
                                                float* __restrict__ topw,
                                                int* __restrict__ chunkCnt) {
  int t = blockIdx.x * 256 + threadIdx.x;
  int bci = t >> 5, p = t & 31;
  const float* xp = &x[(size_t)bci * 512 + p * 16];
  double xl[16];
#pragma unroll
  for (int l = 0; l < 16; ++l) xl[l] = (double)xp[l];
  double lo[8];
  double m = -1e300;
#pragma unroll
  for (int e = 0; e < 8; ++e) {
    double s = bc[e];
#pragma unroll
    for (int l = 0; l < 16; ++l) s += xl[l] * wc[e * 16 + l];
    lo[e] = s;
    m = fmax(m, s);
  }
  double den = 0.0;
#pragma unroll
  for (int e = 0; e < 8; ++e) {
    lo[e] = exp(lo[e] - m);
    den += lo[e];
  }
  int i1 = 0;
  double v1 = lo[0];
#pragma unroll
  for (int e = 1; e < 8; ++e)
    if (lo[e] > v1) { v1 = lo[e]; i1 = e; }
  int i2 = -1;
  double v2 = -1.0;
#pragma unroll
  for (int e = 0; e < 8; ++e)
    if (e != i1 && lo[e] > v2) { v2 = lo[e]; i2 = e; }
  topi[t] = i1 | (i2 << 4);
  topw[2 * t] = (float)(v1 / den);
  topw[2 * t + 1] = (float)(v2 / den);

  __shared__ int wsum[16][4];
  int wave = threadIdx.x >> 6, lane = threadIdx.x & 63;
#pragma unroll
  for (int seg = 0; seg < 16; ++seg) {
    int e = seg & 7;
    bool sel = (seg < 8) ? (i1 == e) : (i2 == e);
    unsigned long long mm = __ballot(sel);
    if (lane == 0) wsum[seg][wave] = __popcll(mm);
  }
  __syncthreads();
  if (threadIdx.x < 16)
    chunkCnt[blockIdx.x * 16 + threadIdx.x] =
        wsum[threadIdx.x][0] + wsum[threadIdx.x][1] + wsum[threadIdx.x][2] + wsum[threadIdx.x][3];
}

// scan: per-segment chunk offsets (LDS-staged), segment bases, tile table, pad fill
__global__ __launch_bounds__(256) void k_scan(const int* __restrict__ chunkCnt,
                                              int* __restrict__ chunkOff,
                                              int* __restrict__ eoff,
                                              int* __restrict__ tileExpert,
                                              int* __restrict__ pairTok,
                                              float* __restrict__ pairW) {
  int tid = threadIdx.x;
  __shared__ int cnt[256 * 16];
  __shared__ int coff[256 * 16];
  for (int i = tid; i < 256 * 16; i += 256) cnt[i] = chunkCnt[i];
  __syncthreads();
  __shared__ int totals[16];
  __shared__ int base[16];
  __shared__ int padded[16];
  if (tid < 16) {
    int run = 0;
    for (int c = 0; c < 256; ++c) {
      coff[c * 16 + tid] = run;
      run += cnt[c * 16 + tid];
    }
    totals[tid] = run;
  }
  __syncthreads();
  for (int i = tid; i < 256 * 16; i += 256) chunkOff[i] = coff[i];
  if (tid == 0) {
    for (int s = 0; s < 2; ++s) {
      int b = s * kTilesPerSlot * 128;
      for (int e = 0; e < 8; ++e) {
        int seg = s * 8 + e;
        base[seg] = b;
        padded[seg] = (totals[seg] + 127) & ~127;
        b += padded[seg];
      }
    }
  }
  __syncthreads();
  if (tid < 16) eoff[tid] = base[tid];
  for (int tI = tid; tI < kMaxTiles; tI += 256) tileExpert[tI] = -1;
  __syncthreads();
  for (int seg = 0; seg < 16; ++seg) {
    int e = seg & 7;
    int tile0 = base[seg] >> 7, nt = padded[seg] >> 7;
    for (int tI = tid; tI < nt; tI += 256) tileExpert[tile0 + tI] = e;
    for (int p = base[seg] + totals[seg] + tid; p < base[seg] + padded[seg]; p += 256) {
      pairTok[p] = -1;  // pad sentinel
      pairW[p] = 0.f;
    }
  }
}

// fill: deterministic token-ordered compaction into per-(slot,expert) segments
__global__ __launch_bounds__(256) void k_fill(const int* __restrict__ topi,
                                              const float* __restrict__ topw,
                                              const int* __restrict__ chunkOff,
                                              const int* __restrict__ eoff,
                                              int* __restrict__ pairTok,
                                              float* __restrict__ pairW) {
  int chunk = blockIdx.x;
  int t = chunk * 256 + threadIdx.x;
  int pk = topi[t];
  int i1 = pk & 15, i2 = (pk >> 4) & 15;
  float w1 = topw[2 * t], w2 = topw[2 * t + 1];
  int wave = threadIdx.x >> 6, lane = threadIdx.x & 63;
  __shared__ int wsum[16][4];
  int pre[16];
  bool sel[16];
#pragma unroll
  for (int seg = 0; seg < 16; ++seg) {
    int e = seg & 7;
    sel[seg] = (seg < 8) ? (i1 == e) : (i2 == e);
    unsigned long long mm = __ballot(sel[seg]);
    pre[seg] = __popcll(mm & ((1ull << lane) - 1));
    if (lane == 0) wsum[seg][wave] = __popcll(mm);
  }
  __syncthreads();
#pragma unroll
  for (int seg = 0; seg < 16; ++seg) {
    if (!sel[seg]) continue;
    int woff = 0;
    for (int w = 0; w < wave; ++w) woff += wsum[seg][w];
    int pos = eoff[seg] + chunkOff[chunk * 16 + seg] + woff + pre[seg];
    pairTok[pos] = t;
    pairW[pos] = (seg < 8) ? w1 : w2;
  }
}

// ---------------- sparse GEMM kernels (128x128xBK=64 bf16 MFMA) ----------------
// BK=64 single-buffer (r10): one barrier pair per 64 MFMA/wave.
// 8-chunk XOR swizzle: physical chunk p at row holds logical p ^ (row&7).
// N-block-fastest grid (r6). launch_bounds (256,2) — (256,3) spills (r11).
// Gateup: direct-store epilogue (r13 A/B: staged epilogue costs +30 µs here).
// Down: staged f32 epilogue (r9 win — scatter-by-token is the bad case).
// Both kernels byte-identical to r13 (best measured: 465 µs, MfmaUtil 37%).

// gu[pairRow][col] = silu(tok[pairTok[row]] @ Wgate[e]^T) * (tok[...] @ Wup[e]^T)
__global__ __launch_bounds__(256, 2) void k_gateup_sp(const __hip_bfloat16* __restrict__ tok,
                                                      const __hip_bfloat16* __restrict__ Wg0,
                                                      const __hip_bfloat16* __restrict__ Wu0,
                                                      const int* __restrict__ pairTok,
                                                      const int* __restrict__ tileExpert,
                                                      __hip_bfloat16* __restrict__ GU) {
  const int tileIdx = blockIdx.x >> 2;
  const int e = tileExpert[tileIdx];
  if (e < 0) return;
  __shared__ __hip_bfloat16 As[128 * 64];   // 16 KB each
  __shared__ __hip_bfloat16 Bgs[128 * 64];
  __shared__ __hip_bfloat16 Bus[128 * 64];
  const int tid = threadIdx.x;
  const int wid = tid >> 6, lane = tid & 63;
  const int tileBase = tileIdx * 128, tileN = (blockIdx.x & 3) * 128;
  const int wr = wid >> 1, wcol = wid & 1;
  const int r = lane & 15, kq = lane >> 4;

  f32x4 accg[4][4] = {};
  f32x4 accu[4][4] = {};

  const char* Ab = (const char*)tok;
  const char* Bgb = (const char*)(Wg0 + (size_t)e * kFF * kH);
  const char* Bub = (const char*)(Wu0 + (size_t)e * kFF * kH);

  int rowS[4], colS[4];
  size_t tokS[4];
#pragma unroll
  for (int s = 0; s < 4; ++s) {
    int off = wid * 1024 + lane * 16 + s * 4096;
    rowS[s] = off >> 7;                         // 128-B rows
    int p = (off & 127) >> 4;                   // physical chunk 0..7
    colS[s] = ((p ^ (rowS[s] & 7)) << 4);       // pre-swizzled global col (bytes)
    int ti = pairTok[tileBase + rowS[s]];
    tokS[s] = (size_t)(ti < 0 ? 0 : ti);
  }

#pragma unroll 1
  for (int kt = 0; kt < 8; ++kt) {
    const int kb = kt * 128;  // byte offset within 1024-B token row
#pragma unroll
    for (int s = 0; s < 4; ++s) {
      GLL16(Ab + tokS[s] * 1024 + kb + colS[s], (char*)As + wid * 1024 + s * 4096);
      GLL16(Bgb + (size_t)(tileN + rowS[s]) * 1024 + kb + colS[s],
            (char*)Bgs + wid * 1024 + s * 4096);
      GLL16(Bub + (size_t)(tileN + rowS[s]) * 1024 + kb + colS[s],
            (char*)Bus + wid * 1024 + s * 4096);
    }
    __syncthreads();

#pragma unroll
    for (int kk = 0; kk < 2; ++kk) {
      short8 a[4], bg[4], bu[4];
#pragma unroll
      for (int i = 0; i < 4; ++i) {
        int row = wr * 64 + i * 16 + r;
        int pc = (kk * 4 + kq) ^ (row & 7);
        a[i] = *(const short8*)&As[row * 64 + pc * 8];
      }
#pragma unroll
      for (int j = 0; j < 4; ++j) {
        int row = wcol * 64 + j * 16 + r;
        int pc = (kk * 4 + kq) ^ (row & 7);
        bg[j] = *(const short8*)&Bgs[row * 64 + pc * 8];
        bu[j] = *(const short8*)&Bus[row * 64 + pc * 8];
      }
#pragma unroll
      for (int i = 0; i < 4; ++i)
#pragma unroll
        for (int j = 0; j < 4; ++j) {
          accg[i][j] = __builtin_amdgcn_mfma_f32_16x16x32_bf16(a[i], bg[j], accg[i][j], 0, 0, 0);
          accu[i][j] = __builtin_amdgcn_mfma_f32_16x16x32_bf16(a[i], bu[j], accu[i][j], 0, 0, 0);
        }
    }
    __syncthreads();
  }

  // direct-store epilogue (r10-proven)
#pragma unroll
  for (int i = 0; i < 4; ++i)
#pragma unroll
    for (int j = 0; j < 4; ++j)
#pragma unroll
      for (int q = 0; q < 4; ++q) {
        int row = tileBase + wr * 64 + i * 16 + kq * 4 + q;
        int col = tileN + wcol * 64 + j * 16 + r;
        float g = accg[i][j][q], u = accu[i][j][q];
        float val = g / (1.f + __expf(-g)) * u;
        GU[(size_t)row * kFF + col] = __float2bfloat16(val);
      }
}

// out[pairTok[row]] (=|+=) pairW[row] * (gu[row] @ Wdown[e]^T)  — no atomics.
__global__ __launch_bounds__(256, 2) void k_down_sp(const __hip_bfloat16* __restrict__ GU,
                                                    const __hip_bfloat16* __restrict__ Wd0,
                                                    const int* __restrict__ pairTok,
                                                    const float* __restrict__ pairW,
                                                    const int* __restrict__ tileExpert,
                                                    float* __restrict__ out,
                                                    float* __restrict__ dump,
                                                    int tileOff, int first) {
  const int tile = tileOff + (blockIdx.x >> 2);
  const int e = tileExpert[tile];
  if (e < 0) return;
  __shared__ __hip_bfloat16 As[128 * 64];
  __shared__ __hip_bfloat16 Bs[128 * 64];
  __shared__ float Cs[32 * 132];  // dedicated epilogue staging (16.9 KB)
  const int tid = threadIdx.x;
  const int wid = tid >> 6, lane = tid & 63;
  const int tileBase = tile * 128, tileN = (blockIdx.x & 3) * 128;
  const int wr = wid >> 1, wcol = wid & 1;
  const int r = lane & 15, kq = lane >> 4;

  f32x4 acc[4][4] = {};

  const char* Ab = (const char*)GU;
  const char* Bb = (const char*)(Wd0 + (size_t)e * kH * kFF);

  int rowS[4], colS[4];
#pragma unroll
  for (int s = 0; s < 4; ++s) {
    int off = wid * 1024 + lane * 16 + s * 4096;
    rowS[s] = off >> 7;
    int p = (off & 127) >> 4;
    colS[s] = ((p ^ (rowS[s] & 7)) << 4);
  }

#pragma unroll 1
  for (int kt = 0; kt < 8; ++kt) {
    const int kb = kt * 128;
#pragma unroll
    for (int s = 0; s < 4; ++s) {
      GLL16(Ab + (size_t)(tileBase + rowS[s]) * 1024 + kb + colS[s],
            (char*)As + wid * 1024 + s * 4096);
      GLL16(Bb + (size_t)(tileN + rowS[s]) * 1024 + kb + colS[s],
            (char*)Bs + wid * 1024 + s * 4096);
    }
    __syncthreads();

#pragma unroll
    for (int kk = 0; kk < 2; ++kk) {
      short8 a[4], b[4];
#pragma unroll
      for (int i = 0; i < 4; ++i) {
        int row = wr * 64 + i * 16 + r;
        int pc = (kk * 4 + kq) ^ (row & 7);
        a[i] = *(const short8*)&As[row * 64 + pc * 8];
      }
#pragma unroll
      for (int j = 0; j < 4; ++j) {
        int row = wcol * 64 + j * 16 + r;
        int pc = (kk * 4 + kq) ^ (row & 7);
        b[j] = *(const short8*)&Bs[row * 64 + pc * 8];
      }
#pragma unroll
      for (int i = 0; i < 4; ++i)
#pragma unroll
        for (int j = 0; j < 4; ++j)
          acc[i][j] = __builtin_amdgcn_mfma_f32_16x16x32_bf16(a[i], b[j], acc[i][j], 0, 0, 0);
    }
    __syncthreads();
  }

  // ---- LDS-transpose epilogue: 4 batches of 32 rows through dedicated Cs
  const int rowl = tid >> 3;            // 0..31
  const int cbase = (tid & 7) * 16;     // 0..112, f32 col within 128
#pragma unroll
  for (int batch = 0; batch < 4; ++batch) {
    __syncthreads();
    if (wr == (batch >> 1)) {
      int bi0 = (batch & 1) * 2;
#pragma unroll
      for (int ii = 0; ii < 2; ++ii) {
        int i = bi0 + ii;
#pragma unroll
        for (int j = 0; j < 4; ++j) {
          int cl = wcol * 64 + j * 16 + r;
#pragma unroll
          for (int q = 0; q < 4; ++q) {
            int rl = ii * 16 + kq * 4 + q;
            Cs[rl * 132 + cl] = acc[i][j][q];
          }
        }
      }
    }
    __syncthreads();
    int prow = tileBase + batch * 32 + rowl;
    float wv = pairW[prow];
    int tk = pairTok[prow];
    float* orow = (tk >= 0) ? out + (size_t)tk * kH + tileN + cbase
                            : dump + (size_t)(prow & 127) * kH + tileN + cbase;
    const float* crow = &Cs[rowl * 132 + cbase];
#pragma unroll
    for (int c = 0; c < 4; ++c) {
      f32x4 v = *(const f32x4*)(crow + c * 4);
      v *= wv;
      if (first) {
        *(f32x4*)(orow + c * 4) = v;
      } else {
        f32x4 o = *(const f32x4*)(orow + c * 4);
        *(f32x4*)(orow + c * 4) = o + v;
      }
    }
  }
}

// ---------------- launcher ----------------
extern "C" void kernel_launch(void* const* d_in, const int* in_sizes, int n_in,
                              void* d_out, int out_size, void* d_ws, size_t ws_size,
                              hipStream_t stream) {
  const float* x = (const float*)d_in[0];
  const float* Wp = (const float*)d_in[1];
  const float* bp = (const float*)d_in[2];
  const float* Wg = (const float*)d_in[3];
  const float* Wgate = (const float*)d_in[4];
  const float* Wup = (const float*)d_in[5];
  const float* Wdown = (const float*)d_in[6];
  float* out = (float*)d_out;

  char* ws = (char*)d_ws;
  __hip_bfloat16* tok = (__hip_bfloat16*)(ws + OFF_TOK);
  __hip_bfloat16* gu = (__hip_bfloat16*)(ws + OFF_GU);
  int* topi = (int*)(ws + OFF_TOPI);
  float* topw = (float*)(ws + OFF_TOPW);
  int* chunkCnt = (int*)(ws + OFF_CCNT);
  int* chunkOff = (int*)(ws + OFF_COFF);
  int* eoff = (int*)(ws + OFF_EOFF);
  int* tileExpert = (int*)(ws + OFF_TILE);
  int* pairTok = (int*)(ws + OFF_PTOK);
  float* pairW = (float*)(ws + OFF_PW);
  float* dump = (float*)(ws + OFF_DUMP);
  __hip_bfloat16* bgw = (__hip_bfloat16*)(ws + OFF_BG);
  __hip_bfloat16* buw = (__hip_bfloat16*)(ws + OFF_BU);
  __hip_bfloat16* bdw = (__hip_bfloat16*)(ws + OFF_BD);
  double* wc = (double*)(ws + OFF_WC);
  double* bcv = (double*)(ws + OFF_BC);

  const int nw = kE * kFF * kH;
  k_conv3<<<2048, 256, 0, stream>>>(Wgate, Wup, Wdown, bgw, buw, bdw, nw);
  k_wcomb<<<1, 256, 0, stream>>>(Wg, Wp, bp, wc, bcv);
  k_patch<<<2048, 256, 0, stream>>>(x, Wp, bp, tok);
  k_router<<<256, 256, 0, stream>>>(x, wc, bcv, topi, topw, chunkCnt);
  k_scan<<<1, 256, 0, stream>>>(chunkCnt, chunkOff, eoff, tileExpert, pairTok, pairW);
  k_fill<<<256, 256, 0, stream>>>(topi, topw, chunkOff, eoff, pairTok, pairW);

  k_gateup_sp<<<kMaxTiles * 4, 256, 0, stream>>>(tok, bgw, buw, pairTok, tileExpert, gu);
  k_down_sp<<<kTilesPerSlot * 4, 256, 0, stream>>>(gu, bdw, pairTok, pairW, tileExpert, out,
                                                   dump, 0, 1);
  k_down_sp<<<kTilesPerSlot * 4, 256, 0, stream>>>(gu, bdw, pairTok, pairW, tileExpert, out,
                                                   dump, kTilesPerSlot, 0);
}